// Round 10
// baseline (3050.127 us; speedup 1.0000x reference)
//
#include <hip/hip_runtime.h>

#define IN_F 128
#define H 64

#define BKT_BITS 7
#define BKT_SZ 128          // dests per bucket
#define NBKT_MAX 1024       // supports N <= 131072
#define CHUNK 8192          // edges per block in P1/P3
#define NCH 16              // source chunks
#define CH_SHIFT 13         // 8192 nodes (1 MB of xs rows) per chunk

using half8 = __attribute__((ext_vector_type(8))) _Float16;
using f32x4 = __attribute__((ext_vector_type(4))) float;

// ---------------- P1: per-bucket edge counts (LDS histogram) ----------------

__global__ void p1_bucket_count(const int* __restrict__ col, int* __restrict__ bucketCnt,
                                int E, int nbkt) {
    __shared__ int h[NBKT_MAX];
    int t = threadIdx.x;
    for (int i = t; i < NBKT_MAX; i += 256) h[i] = 0;
    __syncthreads();
    int beg = blockIdx.x * CHUNK;
    int end = min(E, beg + CHUNK);
    for (int j = beg + t; j < end; j += 256)
        atomicAdd(&h[col[j] >> BKT_BITS], 1);
    __syncthreads();
    for (int i = t; i < nbkt; i += 256)
        if (h[i]) atomicAdd(&bucketCnt[i], h[i]);
}

// ---------------- P2: scan bucket counts -> bases + cursors (1 block, 1024 thr) --------

__global__ void p2_bucket_scan(const int* __restrict__ bucketCnt, int* __restrict__ base,
                               int* __restrict__ cursor, int nbkt) {
    __shared__ int s[NBKT_MAX];
    int t = threadIdx.x;  // 1024 threads
    int v = (t < nbkt) ? bucketCnt[t] : 0;
    s[t] = v;
    __syncthreads();
    for (int off = 1; off < NBKT_MAX; off <<= 1) {
        int tmp = (t >= off) ? s[t - off] : 0;
        __syncthreads();
        s[t] += tmp;
        __syncthreads();
    }
    if (t < nbkt) {
        int b = s[t] - v;  // exclusive
        base[t] = b;
        cursor[t] = b;
    }
    if (t == nbkt - 1) base[nbkt] = s[t];  // == E
}

// ---------------- P3: partition edges, packed (loc<<24 | src) ----------------

__global__ void p3_partition(const int* __restrict__ row, const int* __restrict__ col,
                             int* __restrict__ cursor, int* __restrict__ part,
                             int E, int nbkt) {
    __shared__ int h[NBKT_MAX];
    __shared__ int res[NBKT_MAX];
    int t = threadIdx.x;
    for (int i = t; i < NBKT_MAX; i += 256) h[i] = 0;
    __syncthreads();
    int beg = blockIdx.x * CHUNK;
    int end = min(E, beg + CHUNK);
    for (int j = beg + t; j < end; j += 256)
        atomicAdd(&h[col[j] >> BKT_BITS], 1);
    __syncthreads();
    for (int i = t; i < nbkt; i += 256) {
        int c = h[i];
        res[i] = c ? atomicAdd(&cursor[i], c) : 0;  // one reservation atomic per (block,bucket)
    }
    __syncthreads();
    for (int i = t; i < NBKT_MAX; i += 256) h[i] = 0;  // reuse as local cursor
    __syncthreads();
    for (int j = beg + t; j < end; j += 256) {
        int c = col[j];
        int b = c >> BKT_BITS;
        int l = atomicAdd(&h[b], 1);
        int pk = (int)(((unsigned)(c & (BKT_SZ - 1)) << 24) | (unsigned)row[j]);  // src < 2^24
        part[res[b] + l] = pk;
    }
}

// ---------------- P4: per-bucket counting sort by (src-chunk, loc) + degrees -----------
// Output srcloc: bucket's edges ordered chunk-major (ascending source chunk).

__global__ __launch_bounds__(256) void p4_csr(const int* __restrict__ part,
                                              const int* __restrict__ base,
                                              int* __restrict__ srcloc,
                                              float* __restrict__ dis, int N, int nbkt) {
    __shared__ int cnt[BKT_SZ * NCH];  // 2048
    __shared__ int lofs[256];
    int b = blockIdx.x, t = threadIdx.x;
    int eb = base[b], ee = base[b + 1];
    for (int i = t; i < BKT_SZ * NCH; i += 256) cnt[i] = 0;
    __syncthreads();
    for (int j = eb + t; j < ee; j += 256) {
        int pk = part[j];
        int loc = (unsigned)pk >> 24;
        int ch = (pk & 0xFFFFFF) >> CH_SHIFT;
        atomicAdd(&cnt[ch * BKT_SZ + loc], 1);
    }
    __syncthreads();
    // per-dest degree -> dis
    if (t < BKT_SZ) {
        int d = 0;
#pragma unroll
        for (int ch = 0; ch < NCH; ++ch) d += cnt[ch * BKT_SZ + t];
        int g = (b << BKT_BITS) + t;
        if (g < N) dis[g] = rsqrtf((float)(d + 1));  // +1 self-loop
    }
    __syncthreads();
    // exclusive scan of cnt[0..2048) in index order (chunk-major); thread owns 8
    int b0 = t * 8;
    int s = 0;
#pragma unroll
    for (int i = 0; i < 8; ++i) s += cnt[b0 + i];
    lofs[t] = s;
    __syncthreads();
    for (int off = 1; off < 256; off <<= 1) {
        int tmp = (t >= off) ? lofs[t - off] : 0;
        __syncthreads();
        lofs[t] += tmp;
        __syncthreads();
    }
    int run = lofs[t] - s;
#pragma unroll
    for (int i = 0; i < 8; ++i) {
        int c = cnt[b0 + i];
        cnt[b0 + i] = run;
        run += c;
    }
    __syncthreads();
    for (int j = eb + t; j < ee; j += 256) {
        int pk = part[j];
        int loc = (unsigned)pk >> 24;
        int ch = (pk & 0xFFFFFF) >> CH_SHIFT;
        int pos = atomicAdd(&cnt[ch * BKT_SZ + loc], 1);
        srcloc[eb + pos] = pk;
    }
}

// ---------------- fp16 prep: W1,W2 -> transposed fp16 ----------------

__global__ void prep_w(const float* __restrict__ W1, const float* __restrict__ W2,
                       _Float16* __restrict__ WT1, _Float16* __restrict__ WT2) {
    int t = blockIdx.x * 256 + threadIdx.x;
    int stride = gridDim.x * 256;
    for (int i = t; i < IN_F * H; i += stride) {
        int k = i >> 6, c = i & 63;
        WT1[c * IN_F + k] = (_Float16)W1[i];
    }
    for (int i = t; i < H * H; i += stride) {
        int k = i >> 6, c = i & 63;
        WT2[c * H + k] = (_Float16)W2[i];
    }
}

// ---------------- MFMA GEMMs: no LDS, frags direct from global ----------------
// A[m][k]: lane l holds row m=l&15, k=(l>>4)*8+j ; B from WT rows; C/D verified m89/m91.

__global__ __launch_bounds__(256) void mm1_mfma(const float* __restrict__ x,
                                                const _Float16* __restrict__ WT1,
                                                const float* __restrict__ dis,
                                                _Float16* __restrict__ out, int N) {
    int t = threadIdx.x;
    int w = t >> 6, l = t & 63, lr = l & 15, lg = l >> 4;
    int r0 = blockIdx.x * 64 + w * 16;
    if (r0 >= N) return;
    half8 bfrag[4][4];
#pragma unroll
    for (int ct = 0; ct < 4; ++ct)
#pragma unroll
        for (int ks = 0; ks < 4; ++ks)
            bfrag[ct][ks] = *(const half8*)(WT1 + (size_t)(ct * 16 + lr) * IN_F + ks * 32 + lg * 8);
    int ar = min(r0 + lr, N - 1);
    const float* ap = x + (size_t)ar * IN_F + lg * 8;
    f32x4 acc0 = {0.f, 0.f, 0.f, 0.f}, acc1 = acc0, acc2 = acc0, acc3 = acc0;
#pragma unroll
    for (int ks = 0; ks < 4; ++ks) {
        float4 a0 = *(const float4*)(ap + ks * 32);
        float4 a1 = *(const float4*)(ap + ks * 32 + 4);
        half8 a;
        a[0] = (_Float16)a0.x; a[1] = (_Float16)a0.y; a[2] = (_Float16)a0.z; a[3] = (_Float16)a0.w;
        a[4] = (_Float16)a1.x; a[5] = (_Float16)a1.y; a[6] = (_Float16)a1.z; a[7] = (_Float16)a1.w;
        acc0 = __builtin_amdgcn_mfma_f32_16x16x32_f16(a, bfrag[0][ks], acc0, 0, 0, 0);
        acc1 = __builtin_amdgcn_mfma_f32_16x16x32_f16(a, bfrag[1][ks], acc1, 0, 0, 0);
        acc2 = __builtin_amdgcn_mfma_f32_16x16x32_f16(a, bfrag[2][ks], acc2, 0, 0, 0);
        acc3 = __builtin_amdgcn_mfma_f32_16x16x32_f16(a, bfrag[3][ks], acc3, 0, 0, 0);
    }
#pragma unroll
    for (int reg = 0; reg < 4; ++reg) {
        int r = r0 + lg * 4 + reg;
        if (r < N) {
            float d = dis[r];
            _Float16* o = out + (size_t)r * H + lr;
            o[0]  = (_Float16)(d * acc0[reg]);
            o[16] = (_Float16)(d * acc1[reg]);
            o[32] = (_Float16)(d * acc2[reg]);
            o[48] = (_Float16)(d * acc3[reg]);
        }
    }
}

__global__ __launch_bounds__(256) void mm2_mfma(const _Float16* __restrict__ hh,
                                                const float* __restrict__ b1,
                                                const _Float16* __restrict__ WT2,
                                                const float* __restrict__ dis,
                                                _Float16* __restrict__ out, int N) {
    int t = threadIdx.x;
    int w = t >> 6, l = t & 63, lr = l & 15, lg = l >> 4;
    int r0 = blockIdx.x * 64 + w * 16;
    if (r0 >= N) return;
    half8 bfrag[4][2];
#pragma unroll
    for (int ct = 0; ct < 4; ++ct)
#pragma unroll
        for (int ks = 0; ks < 2; ++ks)
            bfrag[ct][ks] = *(const half8*)(WT2 + (size_t)(ct * 16 + lr) * H + ks * 32 + lg * 8);
    float bias0[8], bias1[8];
#pragma unroll
    for (int j = 0; j < 8; ++j) bias0[j] = b1[lg * 8 + j];
#pragma unroll
    for (int j = 0; j < 8; ++j) bias1[j] = b1[32 + lg * 8 + j];
    int ar = min(r0 + lr, N - 1);
    const _Float16* ap = hh + (size_t)ar * H + lg * 8;
    f32x4 acc0 = {0.f, 0.f, 0.f, 0.f}, acc1 = acc0, acc2 = acc0, acc3 = acc0;
#pragma unroll
    for (int ks = 0; ks < 2; ++ks) {
        half8 a = *(const half8*)(ap + ks * 32);
        half8 af;
#pragma unroll
        for (int j = 0; j < 8; ++j) {
            float v = (float)a[j] + (ks ? bias1[j] : bias0[j]);
            af[j] = (_Float16)fmaxf(v, 0.f);
        }
        acc0 = __builtin_amdgcn_mfma_f32_16x16x32_f16(af, bfrag[0][ks], acc0, 0, 0, 0);
        acc1 = __builtin_amdgcn_mfma_f32_16x16x32_f16(af, bfrag[1][ks], acc1, 0, 0, 0);
        acc2 = __builtin_amdgcn_mfma_f32_16x16x32_f16(af, bfrag[2][ks], acc2, 0, 0, 0);
        acc3 = __builtin_amdgcn_mfma_f32_16x16x32_f16(af, bfrag[3][ks], acc3, 0, 0, 0);
    }
#pragma unroll
    for (int reg = 0; reg < 4; ++reg) {
        int r = r0 + lg * 4 + reg;
        if (r < N) {
            float d = dis[r];
            _Float16* o = out + (size_t)r * H + lr;
            o[0]  = (_Float16)(d * acc0[reg]);
            o[16] = (_Float16)(d * acc1[reg]);
            o[32] = (_Float16)(d * acc2[reg]);
            o[48] = (_Float16)(d * acc3[reg]);
        }
    }
}

// out[r,:] = dis[r] * ((hh[r,:] + b) @ W)   W:[64,4]  hh fp16, out f32
__global__ void mm3(const _Float16* __restrict__ hh, const float* __restrict__ b,
                    const float* __restrict__ W, const float* __restrict__ dis,
                    float* __restrict__ out, int N) {
    __shared__ float Wl[H * 4];
    __shared__ float bl[H];
    int t = threadIdx.x;
    if (t < H * 4) Wl[t] = W[t];
    if (t < H) bl[t] = b[t];
    __syncthreads();
    int c = t & 3, rr = t >> 2;
    int r = blockIdx.x * 64 + rr;
    if (r >= N) return;
    const _Float16* h0 = hh + (size_t)r * H;
    float a = 0;
    for (int k = 0; k < H; k += 8) {
        half8 v = *(const half8*)(h0 + k);
#pragma unroll
        for (int j = 0; j < 8; ++j)
            a += ((float)v[j] + bl[k + j]) * Wl[(k + j) * 4 + c];
    }
    out[(size_t)r * 4 + c] = dis[r] * a;
}

// ---------------- tiled aggregation: LDS f32 accumulators, chunk-major sweep ----------
// One block per 128-dest bucket; all blocks co-resident sweep source chunks in
// lockstep -> active source window stays in each XCD's L2; xs streamed ~once/XCD.

__global__ __launch_bounds__(256) void agg_tiled(const _Float16* __restrict__ xs,
                                                 const int* __restrict__ base,
                                                 const int* __restrict__ srcloc,
                                                 const float* __restrict__ dis,
                                                 _Float16* __restrict__ out, int N) {
    __shared__ float acc[BKT_SZ * 64];  // 32 KB
    int b = blockIdx.x, t = threadIdx.x;
    int lane = t & 63, w = t >> 6;
    int g0 = b << BKT_BITS;
    for (int l = w; l < BKT_SZ; l += 4) {
        int g = g0 + l;
        acc[l * 64 + lane] = (g < N) ? (float)xs[(size_t)g * 64 + lane] : 0.f;  // self term
    }
    __syncthreads();
    int eb = base[b], ee = base[b + 1];
    for (int j = eb + w * 16; j < ee; j += 64) {
        int myj = j + (lane & 15);
        int e = (myj < ee) ? srcloc[myj] : 0;
#pragma unroll
        for (int k = 0; k < 16; ++k) {
            if (j + k < ee) {  // wave-uniform
                int pk = __shfl(e, k);
                int loc = (unsigned)pk >> 24;
                int src = pk & 0xFFFFFF;
                float v = (float)xs[(size_t)src * 64 + lane];
                atomicAdd(&acc[loc * 64 + lane], v);
            }
        }
    }
    __syncthreads();
    for (int l = w; l < BKT_SZ; l += 4) {
        int g = g0 + l;
        if (g < N)
            out[(size_t)g * 64 + lane] = (_Float16)(dis[g] * acc[l * 64 + lane]);
    }
}

// final layer: 4 features f32; same tiled structure; writes b3 + dis*acc
__global__ __launch_bounds__(256) void agg4_tiled(const float* __restrict__ xs,
                                                  const int* __restrict__ base,
                                                  const int* __restrict__ srcloc,
                                                  const float* __restrict__ dis,
                                                  const float* __restrict__ bb,
                                                  float* __restrict__ out, int N) {
    __shared__ float acc[BKT_SZ * 4];  // 2 KB
    int b = blockIdx.x, t = threadIdx.x;
    int g0 = b << BKT_BITS;
    for (int i = t; i < BKT_SZ * 4; i += 256) {
        int g = g0 + (i >> 2);
        acc[i] = (g < N) ? xs[(size_t)g * 4 + (i & 3)] : 0.f;  // self term
    }
    __syncthreads();
    int eb = base[b], ee = base[b + 1];
    int f = t & 3, eo = t >> 2;  // 64 edges per iteration
    for (int j = eb + eo; j < ee; j += 64) {
        int pk = srcloc[j];
        int loc = (unsigned)pk >> 24;
        int src = pk & 0xFFFFFF;
        atomicAdd(&acc[loc * 4 + f], xs[(size_t)src * 4 + f]);
    }
    __syncthreads();
    for (int i = t; i < BKT_SZ * 4; i += 256) {
        int g = g0 + (i >> 2);
        if (g < N) out[(size_t)g * 4 + (i & 3)] = bb[i & 3] + dis[g] * acc[i];
    }
}

// ---------------- host ----------------

extern "C" void kernel_launch(void* const* d_in, const int* in_sizes, int n_in,
                              void* d_out, int out_size, void* d_ws, size_t ws_size,
                              hipStream_t stream) {
    const float* x  = (const float*)d_in[0];
    const int*   ei = (const int*)d_in[1];
    const float* W1 = (const float*)d_in[2];
    const float* b1 = (const float*)d_in[3];
    const float* W2 = (const float*)d_in[4];
    const float* b2 = (const float*)d_in[5];
    const float* W3 = (const float*)d_in[6];
    const float* b3 = (const float*)d_in[7];
    float* out = (float*)d_out;
    (void)n_in; (void)out_size; (void)ws_size;

    const int N = in_sizes[0] / IN_F;
    const int E = in_sizes[1] / 2;
    const int* row = ei;
    const int* col = ei + E;
    const int nbkt = (N + BKT_SZ - 1) >> BKT_BITS;  // 782 for N=100K (<= 1024)

    // workspace carve (all 256B-aligned)
    char* w = (char*)d_ws;
    auto carve = [&](size_t bytes) { char* p = w; w += (bytes + 255) & ~(size_t)255; return p; };
    _Float16* bufX  = (_Float16*)carve((size_t)N * H * 2);     // 12.8 MB (mm out / agg in)
    _Float16* bufY  = (_Float16*)carve((size_t)N * H * 2);     // 12.8 MB (agg out / mm in)
    _Float16* WT1   = (_Float16*)carve((size_t)IN_F * H * 2);
    _Float16* WT2   = (_Float16*)carve((size_t)H * H * 2);
    float*  bufC   = (float*)carve((size_t)N * 4 * 4);         // 1.6 MB
    float*  dis    = (float*)carve((size_t)N * 4);
    int*    srcloc = (int*)carve((size_t)E * 4);               // 12.8 MB (chunk-major packed)
    int*    part   = (int*)carve((size_t)E * 4);               // 12.8 MB (bucket-partitioned)
    int*    bktCnt = (int*)carve((size_t)NBKT_MAX * 4);
    int*    bktBas = (int*)carve((size_t)(NBKT_MAX + 1) * 4);
    int*    bktCur = (int*)carve((size_t)NBKT_MAX * 4);

    (void)hipMemsetAsync(bktCnt, 0, (size_t)nbkt * 4, stream);

    int gE = (E + CHUNK - 1) / CHUNK;  // 391
    int gMM = (N + 63) / 64;           // 1563

    p1_bucket_count<<<gE, 256, 0, stream>>>(col, bktCnt, E, nbkt);
    p2_bucket_scan<<<1, NBKT_MAX, 0, stream>>>(bktCnt, bktBas, bktCur, nbkt);
    p3_partition<<<gE, 256, 0, stream>>>(row, col, bktCur, part, E, nbkt);
    p4_csr<<<nbkt, 256, 0, stream>>>(part, bktBas, srcloc, dis, N, nbkt);

    prep_w<<<48, 256, 0, stream>>>(W1, W2, WT1, WT2);

    // layer 1: bufX = fp16(dis .* (x@W1)) ; agg -> bufY fp16
    mm1_mfma<<<gMM, 256, 0, stream>>>(x, WT1, dis, bufX, N);
    agg_tiled<<<nbkt, 256, 0, stream>>>(bufX, bktBas, srcloc, dis, bufY, N);
    // layer 2: bufX = fp16(dis .* (relu(bufY+b1)@W2)) ; agg -> bufY fp16
    mm2_mfma<<<gMM, 256, 0, stream>>>(bufY, b1, WT2, dis, bufX, N);
    agg_tiled<<<nbkt, 256, 0, stream>>>(bufX, bktBas, srcloc, dis, bufY, N);
    // layer 3: bufC = dis .* ((bufY+b2)@W3) ; agg (+b3) -> out
    mm3<<<gMM, 256, 0, stream>>>(bufY, b2, W3, dis, bufC, N);
    agg4_tiled<<<nbkt, 256, 0, stream>>>(bufC, bktBas, srcloc, dis, b3, out, N);
}

// Round 11
// 450.836 us; speedup vs baseline: 6.7655x; 6.7655x over previous
//
#include <hip/hip_runtime.h>

#define IN_F 128
#define H 64

#define BKT_BITS 8
#define BKT_SZ 256          // nodes per bucket
#define NBKT_MAX 512        // supports N <= 131072
#define CHUNK 8192          // edges per block in P1/P3

using half8 = __attribute__((ext_vector_type(8))) _Float16;
using half4 = __attribute__((ext_vector_type(4))) _Float16;
using f32x4 = __attribute__((ext_vector_type(4))) float;

// ---------------- P1: per-bucket edge counts (LDS histogram) ----------------

__global__ void p1_bucket_count(const int* __restrict__ col, int* __restrict__ bucketCnt,
                                int E, int nbkt) {
    __shared__ int h[NBKT_MAX];
    int t = threadIdx.x;
    for (int i = t; i < NBKT_MAX; i += 256) h[i] = 0;
    __syncthreads();
    int beg = blockIdx.x * CHUNK;
    int end = min(E, beg + CHUNK);
    for (int j = beg + t; j < end; j += 256)
        atomicAdd(&h[col[j] >> BKT_BITS], 1);
    __syncthreads();
    for (int i = t; i < nbkt; i += 256)
        if (h[i]) atomicAdd(&bucketCnt[i], h[i]);
}

// ---------------- P2: scan bucket counts -> bases + cursors (1 block) ----------------

__global__ void p2_bucket_scan(const int* __restrict__ bucketCnt, int* __restrict__ base,
                               int* __restrict__ cursor, int nbkt) {
    __shared__ int s[NBKT_MAX];
    int t = threadIdx.x;  // 512 threads
    int v = (t < nbkt) ? bucketCnt[t] : 0;
    s[t] = v;
    __syncthreads();
    for (int off = 1; off < NBKT_MAX; off <<= 1) {
        int tmp = (t >= off) ? s[t - off] : 0;
        __syncthreads();
        s[t] += tmp;
        __syncthreads();
    }
    if (t < nbkt) {
        int b = s[t] - v;  // exclusive
        base[t] = b;
        cursor[t] = b;
    }
    if (t == nbkt - 1) base[nbkt] = s[t];  // == E
}

// ---------------- P3: partition edges, packed (loc<<24 | src) ----------------

__global__ void p3_partition(const int* __restrict__ row, const int* __restrict__ col,
                             int* __restrict__ cursor, int* __restrict__ part,
                             int E, int nbkt) {
    __shared__ int h[NBKT_MAX];
    __shared__ int res[NBKT_MAX];
    int t = threadIdx.x;
    for (int i = t; i < NBKT_MAX; i += 256) h[i] = 0;
    __syncthreads();
    int beg = blockIdx.x * CHUNK;
    int end = min(E, beg + CHUNK);
    for (int j = beg + t; j < end; j += 256)
        atomicAdd(&h[col[j] >> BKT_BITS], 1);
    __syncthreads();
    for (int i = t; i < nbkt; i += 256) {
        int c = h[i];
        res[i] = c ? atomicAdd(&cursor[i], c) : 0;  // one reservation atomic per (block,bucket)
    }
    __syncthreads();
    for (int i = t; i < NBKT_MAX; i += 256) h[i] = 0;  // reuse as local cursor
    __syncthreads();
    for (int j = beg + t; j < end; j += 256) {
        int c = col[j];
        int b = c >> BKT_BITS;
        int l = atomicAdd(&h[b], 1);
        int pk = (int)(((unsigned)(c & (BKT_SZ - 1)) << 24) | (unsigned)row[j]);  // src < 2^24
        part[res[b] + l] = pk;
    }
}

// ---------------- P4: per-bucket CSR finalize (offs, dis, src) ----------------

__global__ void p4_csr(const int* __restrict__ part, const int* __restrict__ base,
                       int* __restrict__ offs, int* __restrict__ srcb,
                       float* __restrict__ dis, int N, int nbkt) {
    __shared__ int deg[BKT_SZ];
    __shared__ int lofs[BKT_SZ];
    __shared__ int cur[BKT_SZ];
    int b = blockIdx.x, t = threadIdx.x;  // 256 threads
    int eb = base[b], ee = base[b + 1];
    deg[t] = 0;
    __syncthreads();
    for (int j = eb + t; j < ee; j += 256)
        atomicAdd(&deg[(unsigned)part[j] >> 24], 1);
    __syncthreads();
    int v = deg[t];
    lofs[t] = v;
    __syncthreads();
    for (int off = 1; off < BKT_SZ; off <<= 1) {
        int tmp = (t >= off) ? lofs[t - off] : 0;
        __syncthreads();
        lofs[t] += tmp;
        __syncthreads();
    }
    int excl = lofs[t] - v;  // exclusive prefix within bucket
    int g = (b << BKT_BITS) + t;
    if (g < N) {
        offs[g] = eb + excl;
        dis[g] = rsqrtf((float)(v + 1));  // +1 self-loop
    }
    if (b == nbkt - 1 && t == 0) offs[N] = ee;  // == E
    deg[t] = excl;  // repurpose: scatter base per local node
    cur[t] = 0;
    __syncthreads();
    for (int j = eb + t; j < ee; j += 256) {
        int pk = part[j];
        int loc = (unsigned)pk >> 24;
        int l = atomicAdd(&cur[loc], 1);
        srcb[eb + deg[loc] + l] = pk & 0xFFFFFF;  // within-bucket region: L2 write-combined
    }
}

// ---------------- fp16 prep: W1,W2 -> transposed fp16 ----------------

__global__ void prep_w(const float* __restrict__ W1, const float* __restrict__ W2,
                       _Float16* __restrict__ WT1, _Float16* __restrict__ WT2) {
    int t = blockIdx.x * 256 + threadIdx.x;
    int stride = gridDim.x * 256;
    for (int i = t; i < IN_F * H; i += stride) {
        int k = i >> 6, c = i & 63;
        WT1[c * IN_F + k] = (_Float16)W1[i];
    }
    for (int i = t; i < H * H; i += stride) {
        int k = i >> 6, c = i & 63;
        WT2[c * H + k] = (_Float16)W2[i];
    }
}

// ---------------- MFMA GEMMs: no LDS, frags direct from global ----------------
// A[m][k]: lane l holds row m=l&15, k=(l>>4)*8+j ; B from WT rows; C/D verified m89/m91.
// Output stored QUARTER-MAJOR: xsq[q][node][16] halves (q = ct), for L2-resident agg.

__global__ __launch_bounds__(256) void mm1_mfma(const float* __restrict__ x,
                                                const _Float16* __restrict__ WT1,
                                                const float* __restrict__ dis,
                                                _Float16* __restrict__ out, int N) {
    int t = threadIdx.x;
    int w = t >> 6, l = t & 63, lr = l & 15, lg = l >> 4;
    int r0 = blockIdx.x * 64 + w * 16;
    if (r0 >= N) return;
    half8 bfrag[4][4];
#pragma unroll
    for (int ct = 0; ct < 4; ++ct)
#pragma unroll
        for (int ks = 0; ks < 4; ++ks)
            bfrag[ct][ks] = *(const half8*)(WT1 + (size_t)(ct * 16 + lr) * IN_F + ks * 32 + lg * 8);
    int ar = min(r0 + lr, N - 1);
    const float* ap = x + (size_t)ar * IN_F + lg * 8;
    f32x4 acc0 = {0.f, 0.f, 0.f, 0.f}, acc1 = acc0, acc2 = acc0, acc3 = acc0;
#pragma unroll
    for (int ks = 0; ks < 4; ++ks) {
        float4 a0 = *(const float4*)(ap + ks * 32);
        float4 a1 = *(const float4*)(ap + ks * 32 + 4);
        half8 a;
        a[0] = (_Float16)a0.x; a[1] = (_Float16)a0.y; a[2] = (_Float16)a0.z; a[3] = (_Float16)a0.w;
        a[4] = (_Float16)a1.x; a[5] = (_Float16)a1.y; a[6] = (_Float16)a1.z; a[7] = (_Float16)a1.w;
        acc0 = __builtin_amdgcn_mfma_f32_16x16x32_f16(a, bfrag[0][ks], acc0, 0, 0, 0);
        acc1 = __builtin_amdgcn_mfma_f32_16x16x32_f16(a, bfrag[1][ks], acc1, 0, 0, 0);
        acc2 = __builtin_amdgcn_mfma_f32_16x16x32_f16(a, bfrag[2][ks], acc2, 0, 0, 0);
        acc3 = __builtin_amdgcn_mfma_f32_16x16x32_f16(a, bfrag[3][ks], acc3, 0, 0, 0);
    }
    size_t qs = (size_t)N * 16;
#pragma unroll
    for (int reg = 0; reg < 4; ++reg) {
        int r = r0 + lg * 4 + reg;
        if (r < N) {
            float d = dis[r];
            _Float16* o = out + (size_t)r * 16 + lr;
            o[0]      = (_Float16)(d * acc0[reg]);
            o[qs]     = (_Float16)(d * acc1[reg]);
            o[2 * qs] = (_Float16)(d * acc2[reg]);
            o[3 * qs] = (_Float16)(d * acc3[reg]);
        }
    }
}

__global__ __launch_bounds__(256) void mm2_mfma(const _Float16* __restrict__ hh,
                                                const float* __restrict__ b1,
                                                const _Float16* __restrict__ WT2,
                                                const float* __restrict__ dis,
                                                _Float16* __restrict__ out, int N) {
    int t = threadIdx.x;
    int w = t >> 6, l = t & 63, lr = l & 15, lg = l >> 4;
    int r0 = blockIdx.x * 64 + w * 16;
    if (r0 >= N) return;
    half8 bfrag[4][2];
#pragma unroll
    for (int ct = 0; ct < 4; ++ct)
#pragma unroll
        for (int ks = 0; ks < 2; ++ks)
            bfrag[ct][ks] = *(const half8*)(WT2 + (size_t)(ct * 16 + lr) * H + ks * 32 + lg * 8);
    float bias0[8], bias1[8];
#pragma unroll
    for (int j = 0; j < 8; ++j) bias0[j] = b1[lg * 8 + j];
#pragma unroll
    for (int j = 0; j < 8; ++j) bias1[j] = b1[32 + lg * 8 + j];
    int ar = min(r0 + lr, N - 1);
    const _Float16* ap = hh + (size_t)ar * H + lg * 8;
    f32x4 acc0 = {0.f, 0.f, 0.f, 0.f}, acc1 = acc0, acc2 = acc0, acc3 = acc0;
#pragma unroll
    for (int ks = 0; ks < 2; ++ks) {
        half8 a = *(const half8*)(ap + ks * 32);
        half8 af;
#pragma unroll
        for (int j = 0; j < 8; ++j) {
            float v = (float)a[j] + (ks ? bias1[j] : bias0[j]);
            af[j] = (_Float16)fmaxf(v, 0.f);
        }
        acc0 = __builtin_amdgcn_mfma_f32_16x16x32_f16(af, bfrag[0][ks], acc0, 0, 0, 0);
        acc1 = __builtin_amdgcn_mfma_f32_16x16x32_f16(af, bfrag[1][ks], acc1, 0, 0, 0);
        acc2 = __builtin_amdgcn_mfma_f32_16x16x32_f16(af, bfrag[2][ks], acc2, 0, 0, 0);
        acc3 = __builtin_amdgcn_mfma_f32_16x16x32_f16(af, bfrag[3][ks], acc3, 0, 0, 0);
    }
    size_t qs = (size_t)N * 16;
#pragma unroll
    for (int reg = 0; reg < 4; ++reg) {
        int r = r0 + lg * 4 + reg;
        if (r < N) {
            float d = dis[r];
            _Float16* o = out + (size_t)r * 16 + lr;
            o[0]      = (_Float16)(d * acc0[reg]);
            o[qs]     = (_Float16)(d * acc1[reg]);
            o[2 * qs] = (_Float16)(d * acc2[reg]);
            o[3 * qs] = (_Float16)(d * acc3[reg]);
        }
    }
}

// out[r,:] = dis[r] * ((hh[r,:] + b) @ W)   W:[64,4]  hh fp16 rows, out f32
__global__ void mm3(const _Float16* __restrict__ hh, const float* __restrict__ b,
                    const float* __restrict__ W, const float* __restrict__ dis,
                    float* __restrict__ out, int N) {
    __shared__ float Wl[H * 4];
    __shared__ float bl[H];
    int t = threadIdx.x;
    if (t < H * 4) Wl[t] = W[t];
    if (t < H) bl[t] = b[t];
    __syncthreads();
    int c = t & 3, rr = t >> 2;
    int r = blockIdx.x * 64 + rr;
    if (r >= N) return;
    const _Float16* h0 = hh + (size_t)r * H;
    float a = 0;
    for (int k = 0; k < H; k += 8) {
        half8 v = *(const half8*)(h0 + k);
#pragma unroll
        for (int j = 0; j < 8; ++j)
            a += ((float)v[j] + bl[k + j]) * Wl[(k + j) * 4 + c];
    }
    out[(size_t)r * 4 + c] = dis[r] * a;
}

// ---------------- quarter aggregation: 3.2 MB slice is L2-resident per XCD ------------
// xsq = quarter slice base (xsq_all + q*N*16); out = full-width rows, offset +q*16.
// Wave per node: 16 edge slots x 4 lanes (16B row per edge). Register f32 accumulate.

__global__ __launch_bounds__(256) void agg16(const _Float16* __restrict__ xsq,
                                             const int* __restrict__ offs,
                                             const int* __restrict__ src,
                                             const float* __restrict__ dis,
                                             _Float16* __restrict__ out, int N) {
    int wid = (blockIdx.x * 256 + threadIdx.x) >> 6;
    int lane = threadIdx.x & 63;
    if (wid >= N) return;
    int s = lane >> 2;   // edge slot 0..15
    int f = lane & 3;    // 4 halves: quarter-features [4f, 4f+4)
    int beg = offs[wid], end = offs[wid + 1];
    const _Float16* base = xsq + (size_t)f * 4;
    float a0 = 0.f, a1 = 0.f, a2 = 0.f, a3 = 0.f;
    int j = beg;
    for (; j + 31 < end; j += 32) {
        int idx = src[j + (lane & 31)];  // one coalesced load: 32 indices
        int s0 = __shfl(idx, s);
        int s1 = __shfl(idx, s + 16);
        half4 v0 = *(const half4*)(base + (size_t)s0 * 16);
        half4 v1 = *(const half4*)(base + (size_t)s1 * 16);
        a0 += (float)v0[0] + (float)v1[0];
        a1 += (float)v0[1] + (float)v1[1];
        a2 += (float)v0[2] + (float)v1[2];
        a3 += (float)v0[3] + (float)v1[3];
    }
    for (; j + 15 < end; j += 16) {
        int idx = src[j + (lane & 15)];
        int s0 = __shfl(idx, s);
        half4 v0 = *(const half4*)(base + (size_t)s0 * 16);
        a0 += (float)v0[0]; a1 += (float)v0[1]; a2 += (float)v0[2]; a3 += (float)v0[3];
    }
    int jj = j + s;  // tail: one edge per slot (covers up to 15)
    if (jj < end) {
        int sk = src[jj];
        half4 v = *(const half4*)(base + (size_t)sk * 16);
        a0 += (float)v[0]; a1 += (float)v[1]; a2 += (float)v[2]; a3 += (float)v[3];
    }
    // reduce across the 16 slots
    a0 += __shfl_xor(a0, 4); a0 += __shfl_xor(a0, 8); a0 += __shfl_xor(a0, 16); a0 += __shfl_xor(a0, 32);
    a1 += __shfl_xor(a1, 4); a1 += __shfl_xor(a1, 8); a1 += __shfl_xor(a1, 16); a1 += __shfl_xor(a1, 32);
    a2 += __shfl_xor(a2, 4); a2 += __shfl_xor(a2, 8); a2 += __shfl_xor(a2, 16); a2 += __shfl_xor(a2, 32);
    a3 += __shfl_xor(a3, 4); a3 += __shfl_xor(a3, 8); a3 += __shfl_xor(a3, 16); a3 += __shfl_xor(a3, 32);
    if (s == 0) {
        half4 sv = *(const half4*)(base + (size_t)wid * 16);  // self-loop term
        float d = dis[wid];
        half4 o;
        o[0] = (_Float16)(d * ((float)sv[0] + a0));
        o[1] = (_Float16)(d * ((float)sv[1] + a1));
        o[2] = (_Float16)(d * ((float)sv[2] + a2));
        o[3] = (_Float16)(d * ((float)sv[3] + a3));
        *(half4*)(out + (size_t)wid * 64 + f * 4) = o;  // out already offset by q*16
    }
}

// one thread per node, 4 features f32; final output: dis[c]*(inner) + b3
__global__ void agg4(const float* __restrict__ xs, const int* __restrict__ offs,
                     const int* __restrict__ src, const float* __restrict__ dis,
                     const float* __restrict__ b, float* __restrict__ out, int N) {
    int i = blockIdx.x * 256 + threadIdx.x;
    if (i >= N) return;
    float4 v = *(const float4*)(xs + (size_t)i * 4);
    float4 acc = v;  // self-loop term
    int beg = offs[i], end = offs[i + 1];
    int j = beg;
    for (; j + 3 < end; j += 4) {
        int s0 = src[j], s1 = src[j + 1], s2 = src[j + 2], s3 = src[j + 3];
        float4 m0 = *(const float4*)(xs + (size_t)s0 * 4);
        float4 m1 = *(const float4*)(xs + (size_t)s1 * 4);
        float4 m2 = *(const float4*)(xs + (size_t)s2 * 4);
        float4 m3 = *(const float4*)(xs + (size_t)s3 * 4);
        acc.x += m0.x + m1.x + m2.x + m3.x;
        acc.y += m0.y + m1.y + m2.y + m3.y;
        acc.z += m0.z + m1.z + m2.z + m3.z;
        acc.w += m0.w + m1.w + m2.w + m3.w;
    }
    for (; j < end; ++j) {
        float4 m = *(const float4*)(xs + (size_t)src[j] * 4);
        acc.x += m.x; acc.y += m.y; acc.z += m.z; acc.w += m.w;
    }
    float d = dis[i];
    float4 o;
    o.x = b[0] + d * acc.x;
    o.y = b[1] + d * acc.y;
    o.z = b[2] + d * acc.z;
    o.w = b[3] + d * acc.w;
    *(float4*)(out + (size_t)i * 4) = o;
}

// ---------------- host ----------------

extern "C" void kernel_launch(void* const* d_in, const int* in_sizes, int n_in,
                              void* d_out, int out_size, void* d_ws, size_t ws_size,
                              hipStream_t stream) {
    const float* x  = (const float*)d_in[0];
    const int*   ei = (const int*)d_in[1];
    const float* W1 = (const float*)d_in[2];
    const float* b1 = (const float*)d_in[3];
    const float* W2 = (const float*)d_in[4];
    const float* b2 = (const float*)d_in[5];
    const float* W3 = (const float*)d_in[6];
    const float* b3 = (const float*)d_in[7];
    float* out = (float*)d_out;
    (void)n_in; (void)out_size; (void)ws_size;

    const int N = in_sizes[0] / IN_F;
    const int E = in_sizes[1] / 2;
    const int* row = ei;
    const int* col = ei + E;
    const int nbkt = (N + BKT_SZ - 1) >> BKT_BITS;  // 391 for N=100K (<= 512)

    // workspace carve (all 256B-aligned)
    char* w = (char*)d_ws;
    auto carve = [&](size_t bytes) { char* p = w; w += (bytes + 255) & ~(size_t)255; return p; };
    _Float16* bufXq = (_Float16*)carve((size_t)N * H * 2);     // 12.8 MB (quarter-major xs)
    _Float16* bufY  = (_Float16*)carve((size_t)N * H * 2);     // 12.8 MB (full rows, agg out)
    _Float16* WT1   = (_Float16*)carve((size_t)IN_F * H * 2);
    _Float16* WT2   = (_Float16*)carve((size_t)H * H * 2);
    float*  bufC   = (float*)carve((size_t)N * 4 * 4);         // 1.6 MB
    float*  dis    = (float*)carve((size_t)N * 4);
    int*    offs   = (int*)carve((size_t)(N + 1) * 4);
    int*    srcb   = (int*)carve((size_t)E * 4);               // 12.8 MB
    int*    part   = (int*)carve((size_t)E * 4);               // 12.8 MB (packed loc|src)
    int*    bktCnt = (int*)carve((size_t)NBKT_MAX * 4);
    int*    bktBas = (int*)carve((size_t)(NBKT_MAX + 1) * 4);
    int*    bktCur = (int*)carve((size_t)NBKT_MAX * 4);

    (void)hipMemsetAsync(bktCnt, 0, (size_t)nbkt * 4, stream);

    int gE = (E + CHUNK - 1) / CHUNK;  // 391
    int gN = (N + 255) / 256;
    int gMM = (N + 63) / 64;           // 1563
    int gAG = (N + 3) / 4;
    size_t qs = (size_t)N * 16;

    p1_bucket_count<<<gE, 256, 0, stream>>>(col, bktCnt, E, nbkt);
    p2_bucket_scan<<<1, NBKT_MAX, 0, stream>>>(bktCnt, bktBas, bktCur, nbkt);
    p3_partition<<<gE, 256, 0, stream>>>(row, col, bktCur, part, E, nbkt);
    p4_csr<<<nbkt, BKT_SZ, 0, stream>>>(part, bktBas, offs, srcb, dis, N, nbkt);

    prep_w<<<48, 256, 0, stream>>>(W1, W2, WT1, WT2);

    // layer 1: bufXq = fp16(dis .* (x@W1)) quarter-major ; 4 quarter agg passes -> bufY rows
    mm1_mfma<<<gMM, 256, 0, stream>>>(x, WT1, dis, bufXq, N);
    for (int q = 0; q < 4; ++q)
        agg16<<<gAG, 256, 0, stream>>>(bufXq + q * qs, offs, srcb, dis, bufY + q * 16, N);
    // layer 2: bufXq = fp16(dis .* (relu(bufY+b1)@W2)) quarter-major ; agg -> bufY rows
    mm2_mfma<<<gMM, 256, 0, stream>>>(bufY, b1, WT2, dis, bufXq, N);
    for (int q = 0; q < 4; ++q)
        agg16<<<gAG, 256, 0, stream>>>(bufXq + q * qs, offs, srcb, dis, bufY + q * 16, N);
    // layer 3: bufC = dis .* ((bufY+b2)@W3) ; agg (+b3) -> out
    mm3<<<gMM, 256, 0, stream>>>(bufY, b2, W3, dis, bufC, N);
    agg4<<<gN, 256, 0, stream>>>(bufC, offs, srcb, dis, b3, out, N);
}

// Round 12
// 304.945 us; speedup vs baseline: 10.0022x; 1.4784x over previous
//
#include <hip/hip_runtime.h>

#define IN_F 128
#define H 64

#define BKT_BITS 8
#define BKT_SZ 256          // nodes per bucket
#define NBKT_MAX 512        // supports N <= 131072
#define CHUNK 8192          // edges per block in P1/P3

using half8 = __attribute__((ext_vector_type(8))) _Float16;
using half4 = __attribute__((ext_vector_type(4))) _Float16;
using f32x4 = __attribute__((ext_vector_type(4))) float;

// ---------------- P1: per-bucket edge counts (LDS histogram, 1024 thr) ----------------

__global__ __launch_bounds__(1024) void p1_bucket_count(const int* __restrict__ col,
                                                        int* __restrict__ bucketCnt,
                                                        int E, int nbkt) {
    __shared__ int h[NBKT_MAX];
    int t = threadIdx.x;
    for (int i = t; i < NBKT_MAX; i += 1024) h[i] = 0;
    __syncthreads();
    int beg = blockIdx.x * CHUNK;
    int end = min(E, beg + CHUNK);
    for (int j = beg + t; j < end; j += 1024)
        atomicAdd(&h[col[j] >> BKT_BITS], 1);
    __syncthreads();
    for (int i = t; i < nbkt; i += 1024)
        if (h[i]) atomicAdd(&bucketCnt[i], h[i]);
}

// ---------------- P2: scan bucket counts -> bases + cursors (1 block) ----------------

__global__ void p2_bucket_scan(const int* __restrict__ bucketCnt, int* __restrict__ base,
                               int* __restrict__ cursor, int nbkt) {
    __shared__ int s[NBKT_MAX];
    int t = threadIdx.x;  // 512 threads
    int v = (t < nbkt) ? bucketCnt[t] : 0;
    s[t] = v;
    __syncthreads();
    for (int off = 1; off < NBKT_MAX; off <<= 1) {
        int tmp = (t >= off) ? s[t - off] : 0;
        __syncthreads();
        s[t] += tmp;
        __syncthreads();
    }
    if (t < nbkt) {
        int b = s[t] - v;  // exclusive
        base[t] = b;
        cursor[t] = b;
    }
    if (t == nbkt - 1) base[nbkt] = s[t];  // == E
}

// ---------------- P3: partition edges, packed (loc<<24 | src), 1024 thr ----------------

__global__ __launch_bounds__(1024) void p3_partition(const int* __restrict__ row,
                                                     const int* __restrict__ col,
                                                     int* __restrict__ cursor,
                                                     int* __restrict__ part,
                                                     int E, int nbkt) {
    __shared__ int h[NBKT_MAX];
    __shared__ int res[NBKT_MAX];
    int t = threadIdx.x;
    for (int i = t; i < NBKT_MAX; i += 1024) h[i] = 0;
    __syncthreads();
    int beg = blockIdx.x * CHUNK;
    int end = min(E, beg + CHUNK);
    for (int j = beg + t; j < end; j += 1024)
        atomicAdd(&h[col[j] >> BKT_BITS], 1);
    __syncthreads();
    for (int i = t; i < nbkt; i += 1024) {
        int c = h[i];
        res[i] = c ? atomicAdd(&cursor[i], c) : 0;  // one reservation atomic per (block,bucket)
    }
    __syncthreads();
    for (int i = t; i < NBKT_MAX; i += 1024) h[i] = 0;  // reuse as local cursor
    __syncthreads();
    for (int j = beg + t; j < end; j += 1024) {
        int c = col[j];
        int b = c >> BKT_BITS;
        int l = atomicAdd(&h[b], 1);
        int pk = (int)(((unsigned)(c & (BKT_SZ - 1)) << 24) | (unsigned)row[j]);  // src < 2^24
        part[res[b] + l] = pk;
    }
}

// ---------------- P4: per-bucket CSR finalize (offs, dis, src), 1024 thr ----------------

__global__ __launch_bounds__(1024) void p4_csr(const int* __restrict__ part,
                                               const int* __restrict__ base,
                                               int* __restrict__ offs, int* __restrict__ srcb,
                                               float* __restrict__ dis, int N, int nbkt) {
    __shared__ int deg[BKT_SZ];
    __shared__ int lofs[BKT_SZ];
    __shared__ int cur[BKT_SZ];
    int b = blockIdx.x, t = threadIdx.x;  // 1024 threads
    int eb = base[b], ee = base[b + 1];
    if (t < BKT_SZ) deg[t] = 0;
    __syncthreads();
    for (int j = eb + t; j < ee; j += 1024)
        atomicAdd(&deg[(unsigned)part[j] >> 24], 1);
    __syncthreads();
    int v = 0;
    if (t < BKT_SZ) { v = deg[t]; lofs[t] = v; }
    __syncthreads();
    for (int off = 1; off < BKT_SZ; off <<= 1) {
        int tmp = (t >= off && t < BKT_SZ) ? lofs[t - off] : 0;
        __syncthreads();
        if (t < BKT_SZ) lofs[t] += tmp;
        __syncthreads();
    }
    if (t < BKT_SZ) {
        int excl = lofs[t] - v;  // exclusive prefix within bucket
        int g = (b << BKT_BITS) + t;
        if (g < N) {
            offs[g] = eb + excl;
            dis[g] = rsqrtf((float)(v + 1));  // +1 self-loop
        }
        deg[t] = excl;  // repurpose: scatter base per local node
        cur[t] = 0;
    }
    if (b == nbkt - 1 && t == 0) offs[N] = ee;  // == E
    __syncthreads();
    for (int j = eb + t; j < ee; j += 1024) {
        int pk = part[j];
        int loc = (unsigned)pk >> 24;
        int l = atomicAdd(&cur[loc], 1);
        srcb[eb + deg[loc] + l] = pk & 0xFFFFFF;  // within-bucket region: L2 write-combined
    }
}

// ---------------- fp16 prep: W1,W2 -> transposed fp16 ----------------

__global__ void prep_w(const float* __restrict__ W1, const float* __restrict__ W2,
                       _Float16* __restrict__ WT1, _Float16* __restrict__ WT2) {
    int t = blockIdx.x * 256 + threadIdx.x;
    int stride = gridDim.x * 256;
    for (int i = t; i < IN_F * H; i += stride) {
        int k = i >> 6, c = i & 63;
        WT1[c * IN_F + k] = (_Float16)W1[i];
    }
    for (int i = t; i < H * H; i += stride) {
        int k = i >> 6, c = i & 63;
        WT2[c * H + k] = (_Float16)W2[i];
    }
}

// ---------------- MFMA GEMMs: no LDS, frags direct from global ----------------
// A[m][k]: lane l holds row m=l&15, k=(l>>4)*8+j ; B from WT rows; C/D verified m89/m91.

__global__ __launch_bounds__(256) void mm1_mfma(const float* __restrict__ x,
                                                const _Float16* __restrict__ WT1,
                                                const float* __restrict__ dis,
                                                _Float16* __restrict__ out, int N) {
    int t = threadIdx.x;
    int w = t >> 6, l = t & 63, lr = l & 15, lg = l >> 4;
    int r0 = blockIdx.x * 64 + w * 16;
    if (r0 >= N) return;
    half8 bfrag[4][4];
#pragma unroll
    for (int ct = 0; ct < 4; ++ct)
#pragma unroll
        for (int ks = 0; ks < 4; ++ks)
            bfrag[ct][ks] = *(const half8*)(WT1 + (size_t)(ct * 16 + lr) * IN_F + ks * 32 + lg * 8);
    int ar = min(r0 + lr, N - 1);
    const float* ap = x + (size_t)ar * IN_F + lg * 8;
    f32x4 acc0 = {0.f, 0.f, 0.f, 0.f}, acc1 = acc0, acc2 = acc0, acc3 = acc0;
#pragma unroll
    for (int ks = 0; ks < 4; ++ks) {
        float4 a0 = *(const float4*)(ap + ks * 32);
        float4 a1 = *(const float4*)(ap + ks * 32 + 4);
        half8 a;
        a[0] = (_Float16)a0.x; a[1] = (_Float16)a0.y; a[2] = (_Float16)a0.z; a[3] = (_Float16)a0.w;
        a[4] = (_Float16)a1.x; a[5] = (_Float16)a1.y; a[6] = (_Float16)a1.z; a[7] = (_Float16)a1.w;
        acc0 = __builtin_amdgcn_mfma_f32_16x16x32_f16(a, bfrag[0][ks], acc0, 0, 0, 0);
        acc1 = __builtin_amdgcn_mfma_f32_16x16x32_f16(a, bfrag[1][ks], acc1, 0, 0, 0);
        acc2 = __builtin_amdgcn_mfma_f32_16x16x32_f16(a, bfrag[2][ks], acc2, 0, 0, 0);
        acc3 = __builtin_amdgcn_mfma_f32_16x16x32_f16(a, bfrag[3][ks], acc3, 0, 0, 0);
    }
#pragma unroll
    for (int reg = 0; reg < 4; ++reg) {
        int r = r0 + lg * 4 + reg;
        if (r < N) {
            float d = dis[r];
            _Float16* o = out + (size_t)r * H + lr;
            o[0]  = (_Float16)(d * acc0[reg]);
            o[16] = (_Float16)(d * acc1[reg]);
            o[32] = (_Float16)(d * acc2[reg]);
            o[48] = (_Float16)(d * acc3[reg]);
        }
    }
}

__global__ __launch_bounds__(256) void mm2_mfma(const _Float16* __restrict__ hh,
                                                const float* __restrict__ b1,
                                                const _Float16* __restrict__ WT2,
                                                const float* __restrict__ dis,
                                                _Float16* __restrict__ out, int N) {
    int t = threadIdx.x;
    int w = t >> 6, l = t & 63, lr = l & 15, lg = l >> 4;
    int r0 = blockIdx.x * 64 + w * 16;
    if (r0 >= N) return;
    half8 bfrag[4][2];
#pragma unroll
    for (int ct = 0; ct < 4; ++ct)
#pragma unroll
        for (int ks = 0; ks < 2; ++ks)
            bfrag[ct][ks] = *(const half8*)(WT2 + (size_t)(ct * 16 + lr) * H + ks * 32 + lg * 8);
    float bias0[8], bias1[8];
#pragma unroll
    for (int j = 0; j < 8; ++j) bias0[j] = b1[lg * 8 + j];
#pragma unroll
    for (int j = 0; j < 8; ++j) bias1[j] = b1[32 + lg * 8 + j];
    int ar = min(r0 + lr, N - 1);
    const _Float16* ap = hh + (size_t)ar * H + lg * 8;
    f32x4 acc0 = {0.f, 0.f, 0.f, 0.f}, acc1 = acc0, acc2 = acc0, acc3 = acc0;
#pragma unroll
    for (int ks = 0; ks < 2; ++ks) {
        half8 a = *(const half8*)(ap + ks * 32);
        half8 af;
#pragma unroll
        for (int j = 0; j < 8; ++j) {
            float v = (float)a[j] + (ks ? bias1[j] : bias0[j]);
            af[j] = (_Float16)fmaxf(v, 0.f);
        }
        acc0 = __builtin_amdgcn_mfma_f32_16x16x32_f16(af, bfrag[0][ks], acc0, 0, 0, 0);
        acc1 = __builtin_amdgcn_mfma_f32_16x16x32_f16(af, bfrag[1][ks], acc1, 0, 0, 0);
        acc2 = __builtin_amdgcn_mfma_f32_16x16x32_f16(af, bfrag[2][ks], acc2, 0, 0, 0);
        acc3 = __builtin_amdgcn_mfma_f32_16x16x32_f16(af, bfrag[3][ks], acc3, 0, 0, 0);
    }
#pragma unroll
    for (int reg = 0; reg < 4; ++reg) {
        int r = r0 + lg * 4 + reg;
        if (r < N) {
            float d = dis[r];
            _Float16* o = out + (size_t)r * H + lr;
            o[0]  = (_Float16)(d * acc0[reg]);
            o[16] = (_Float16)(d * acc1[reg]);
            o[32] = (_Float16)(d * acc2[reg]);
            o[48] = (_Float16)(d * acc3[reg]);
        }
    }
}

// out[r,:] = dis[r] * ((hh[r,:] + b) @ W)   W:[64,4]  hh fp16, out f32
__global__ void mm3(const _Float16* __restrict__ hh, const float* __restrict__ b,
                    const float* __restrict__ W, const float* __restrict__ dis,
                    float* __restrict__ out, int N) {
    __shared__ float Wl[H * 4];
    __shared__ float bl[H];
    int t = threadIdx.x;
    if (t < H * 4) Wl[t] = W[t];
    if (t < H) bl[t] = b[t];
    __syncthreads();
    int c = t & 3, rr = t >> 2;
    int r = blockIdx.x * 64 + rr;
    if (r >= N) return;
    const _Float16* h0 = hh + (size_t)r * H;
    float a = 0;
    for (int k = 0; k < H; k += 8) {
        half8 v = *(const half8*)(h0 + k);
#pragma unroll
        for (int j = 0; j < 8; ++j)
            a += ((float)v[j] + bl[k + j]) * Wl[(k + j) * 4 + c];
    }
    out[(size_t)r * 4 + c] = dis[r] * a;
}

// ---------------- aggregation (gather over CSR) ----------------

// one wave per node; lane = (slot s = lane>>4, feature-quad f = lane&15 -> 8B).
// Per 32-edge iter: ONE coalesced nontemporal index load + shfl + 8 gather instrs
// (each gather: 4 rows x 128B = 512B). Index stream bypasses L2 to keep xs resident.
__global__ void agg64h(const _Float16* __restrict__ xs, const int* __restrict__ offs,
                       const int* __restrict__ src, const float* __restrict__ dis,
                       _Float16* __restrict__ out, int N) {
    int wid = (blockIdx.x * 256 + threadIdx.x) >> 6;
    int lane = threadIdx.x & 63;
    if (wid >= N) return;
    int s = lane >> 4;   // slot 0..3 (8 edges each per iter)
    int f = lane & 15;   // feature quad: halves [4f, 4f+4)
    int beg = offs[wid], end = offs[wid + 1];
    int deg = end - beg;
    const _Float16* base = xs + (size_t)f * 4;
    float a0 = 0.f, a1 = 0.f, a2 = 0.f, a3 = 0.f;
    int nfull = deg >> 5;
    int j = beg;
    for (int it = 0; it < nfull; ++it, j += 32) {
        int idx = __builtin_nontemporal_load(src + j + (lane & 31));  // 32 indices, L2-bypass
#pragma unroll
        for (int k = 0; k < 8; ++k) {
            int sk = __shfl(idx, s * 8 + k);
            half4 v = *(const half4*)(base + (size_t)sk * 64);
            a0 += (float)v[0]; a1 += (float)v[1]; a2 += (float)v[2]; a3 += (float)v[3];
        }
    }
    for (int jj = j + s; jj < end; jj += 4) {  // tail: slots round-robin
        int sk = src[jj];
        half4 v = *(const half4*)(base + (size_t)sk * 64);
        a0 += (float)v[0]; a1 += (float)v[1]; a2 += (float)v[2]; a3 += (float)v[3];
    }
    // combine the 4 slots
    a0 += __shfl_xor(a0, 16); a0 += __shfl_xor(a0, 32);
    a1 += __shfl_xor(a1, 16); a1 += __shfl_xor(a1, 32);
    a2 += __shfl_xor(a2, 16); a2 += __shfl_xor(a2, 32);
    a3 += __shfl_xor(a3, 16); a3 += __shfl_xor(a3, 32);
    if (s == 0) {
        half4 sv = *(const half4*)(base + (size_t)wid * 64);  // self-loop term
        float d = dis[wid];
        half4 o;
        o[0] = (_Float16)(d * ((float)sv[0] + a0));
        o[1] = (_Float16)(d * ((float)sv[1] + a1));
        o[2] = (_Float16)(d * ((float)sv[2] + a2));
        o[3] = (_Float16)(d * ((float)sv[3] + a3));
        *(half4*)(out + (size_t)wid * 64 + f * 4) = o;
    }
}

// one thread per node, 4 features f32; final output: dis[c]*(inner) + b3
__global__ void agg4(const float* __restrict__ xs, const int* __restrict__ offs,
                     const int* __restrict__ src, const float* __restrict__ dis,
                     const float* __restrict__ b, float* __restrict__ out, int N) {
    int i = blockIdx.x * 256 + threadIdx.x;
    if (i >= N) return;
    float4 v = *(const float4*)(xs + (size_t)i * 4);
    float4 acc = v;  // self-loop term
    int beg = offs[i], end = offs[i + 1];
    int j = beg;
    for (; j + 3 < end; j += 4) {
        int s0 = src[j], s1 = src[j + 1], s2 = src[j + 2], s3 = src[j + 3];
        float4 m0 = *(const float4*)(xs + (size_t)s0 * 4);
        float4 m1 = *(const float4*)(xs + (size_t)s1 * 4);
        float4 m2 = *(const float4*)(xs + (size_t)s2 * 4);
        float4 m3 = *(const float4*)(xs + (size_t)s3 * 4);
        acc.x += m0.x + m1.x + m2.x + m3.x;
        acc.y += m0.y + m1.y + m2.y + m3.y;
        acc.z += m0.z + m1.z + m2.z + m3.z;
        acc.w += m0.w + m1.w + m2.w + m3.w;
    }
    for (; j < end; ++j) {
        float4 m = *(const float4*)(xs + (size_t)src[j] * 4);
        acc.x += m.x; acc.y += m.y; acc.z += m.z; acc.w += m.w;
    }
    float d = dis[i];
    float4 o;
    o.x = b[0] + d * acc.x;
    o.y = b[1] + d * acc.y;
    o.z = b[2] + d * acc.z;
    o.w = b[3] + d * acc.w;
    *(float4*)(out + (size_t)i * 4) = o;
}

// ---------------- host ----------------

extern "C" void kernel_launch(void* const* d_in, const int* in_sizes, int n_in,
                              void* d_out, int out_size, void* d_ws, size_t ws_size,
                              hipStream_t stream) {
    const float* x  = (const float*)d_in[0];
    const int*   ei = (const int*)d_in[1];
    const float* W1 = (const float*)d_in[2];
    const float* b1 = (const float*)d_in[3];
    const float* W2 = (const float*)d_in[4];
    const float* b2 = (const float*)d_in[5];
    const float* W3 = (const float*)d_in[6];
    const float* b3 = (const float*)d_in[7];
    float* out = (float*)d_out;
    (void)n_in; (void)out_size; (void)ws_size;

    const int N = in_sizes[0] / IN_F;
    const int E = in_sizes[1] / 2;
    const int* row = ei;
    const int* col = ei + E;
    const int nbkt = (N + BKT_SZ - 1) >> BKT_BITS;  // 391 for N=100K (<= 512)

    // workspace carve (all 256B-aligned)
    char* w = (char*)d_ws;
    auto carve = [&](size_t bytes) { char* p = w; w += (bytes + 255) & ~(size_t)255; return p; };
    _Float16* bufX  = (_Float16*)carve((size_t)N * H * 2);     // 12.8 MB (mm out / agg in)
    _Float16* bufY  = (_Float16*)carve((size_t)N * H * 2);     // 12.8 MB (agg out / mm in)
    _Float16* WT1   = (_Float16*)carve((size_t)IN_F * H * 2);
    _Float16* WT2   = (_Float16*)carve((size_t)H * H * 2);
    float*  bufC   = (float*)carve((size_t)N * 4 * 4);         // 1.6 MB
    float*  dis    = (float*)carve((size_t)N * 4);
    int*    offs   = (int*)carve((size_t)(N + 1) * 4);
    int*    srcb   = (int*)carve((size_t)E * 4);               // 12.8 MB
    int*    part   = (int*)carve((size_t)E * 4);               // 12.8 MB (packed loc|src)
    int*    bktCnt = (int*)carve((size_t)NBKT_MAX * 4);
    int*    bktBas = (int*)carve((size_t)(NBKT_MAX + 1) * 4);
    int*    bktCur = (int*)carve((size_t)NBKT_MAX * 4);

    (void)hipMemsetAsync(bktCnt, 0, (size_t)nbkt * 4, stream);

    int gE = (E + CHUNK - 1) / CHUNK;  // 391
    int gN = (N + 255) / 256;
    int gMM = (N + 63) / 64;           // 1563
    int gAG = (N + 3) / 4;

    p1_bucket_count<<<gE, 1024, 0, stream>>>(col, bktCnt, E, nbkt);
    p2_bucket_scan<<<1, NBKT_MAX, 0, stream>>>(bktCnt, bktBas, bktCur, nbkt);
    p3_partition<<<gE, 1024, 0, stream>>>(row, col, bktCur, part, E, nbkt);
    p4_csr<<<nbkt, 1024, 0, stream>>>(part, bktBas, offs, srcb, dis, N, nbkt);

    prep_w<<<48, 256, 0, stream>>>(W1, W2, WT1, WT2);

    // layer 1: bufX = fp16(dis .* (x@W1)) ; agg -> bufY fp16
    mm1_mfma<<<gMM, 256, 0, stream>>>(x, WT1, dis, bufX, N);
    agg64h<<<gAG, 256, 0, stream>>>(bufX, offs, srcb, dis, bufY, N);
    // layer 2: bufX = fp16(dis .* (relu(bufY+b1)@W2)) ; agg -> bufY fp16
    mm2_mfma<<<gMM, 256, 0, stream>>>(bufY, b1, WT2, dis, bufX, N);
    agg64h<<<gAG, 256, 0, stream>>>(bufX, offs, srcb, dis, bufY, N);
    // layer 3: bufC = dis .* ((bufY+b2)@W3) ; agg (+b3) -> out
    mm3<<<gMM, 256, 0, stream>>>(bufY, b2, W3, dis, bufC, N);
    agg4<<<gN, 256, 0, stream>>>(bufC, offs, srcb, dis, b3, out, N);
}

// Round 13
// 291.350 us; speedup vs baseline: 10.4690x; 1.0467x over previous
//
#include <hip/hip_runtime.h>

#define IN_F 128
#define H 64

#define BKT_BITS 8
#define BKT_SZ 256          // nodes per bucket
#define NBKT_MAX 512        // supports N <= 131072
#define CHUNK 8192          // edges per block in P1/P3

using half8 = __attribute__((ext_vector_type(8))) _Float16;
using half4 = __attribute__((ext_vector_type(4))) _Float16;
using f32x4 = __attribute__((ext_vector_type(4))) float;

// ---------------- P1: per-bucket edge counts (LDS histogram) + fused weight prep ------

__global__ __launch_bounds__(1024) void p1_bucket_count(const int* __restrict__ col,
                                                        int* __restrict__ bucketCnt,
                                                        int E, int nbkt, int gE,
                                                        const float* __restrict__ W1,
                                                        const float* __restrict__ W2,
                                                        _Float16* __restrict__ WT1,
                                                        _Float16* __restrict__ WT2) {
    int t = threadIdx.x;
    if (blockIdx.x >= gE) {
        // weight transpose+convert: 12 blocks x 1024 = 12288 = 8192 (W1) + 4096 (W2)
        int i = (blockIdx.x - gE) * 1024 + t;
        if (i < IN_F * H) {
            int k = i >> 6, c = i & 63;
            WT1[c * IN_F + k] = (_Float16)W1[i];
        } else {
            int j = i - IN_F * H;  // < H*H
            int k = j >> 6, c = j & 63;
            WT2[c * H + k] = (_Float16)W2[j];
        }
        return;
    }
    __shared__ int h[NBKT_MAX];
    for (int i = t; i < NBKT_MAX; i += 1024) h[i] = 0;
    __syncthreads();
    int beg = blockIdx.x * CHUNK;
    int end = min(E, beg + CHUNK);
    for (int j = beg + t; j < end; j += 1024)
        atomicAdd(&h[col[j] >> BKT_BITS], 1);
    __syncthreads();
    for (int i = t; i < nbkt; i += 1024)
        if (h[i]) atomicAdd(&bucketCnt[i], h[i]);
}

// ---------------- P2: scan bucket counts -> bases + cursors (1 block) ----------------

__global__ void p2_bucket_scan(const int* __restrict__ bucketCnt, int* __restrict__ base,
                               int* __restrict__ cursor, int nbkt) {
    __shared__ int s[NBKT_MAX];
    int t = threadIdx.x;  // 512 threads
    int v = (t < nbkt) ? bucketCnt[t] : 0;
    s[t] = v;
    __syncthreads();
    for (int off = 1; off < NBKT_MAX; off <<= 1) {
        int tmp = (t >= off) ? s[t - off] : 0;
        __syncthreads();
        s[t] += tmp;
        __syncthreads();
    }
    if (t < nbkt) {
        int b = s[t] - v;  // exclusive
        base[t] = b;
        cursor[t] = b;
    }
    if (t == nbkt - 1) base[nbkt] = s[t];  // == E
}

// ---------------- P3: partition edges, packed (loc<<24 | src), 1024 thr ----------------

__global__ __launch_bounds__(1024) void p3_partition(const int* __restrict__ row,
                                                     const int* __restrict__ col,
                                                     int* __restrict__ cursor,
                                                     int* __restrict__ part,
                                                     int E, int nbkt) {
    __shared__ int h[NBKT_MAX];
    __shared__ int res[NBKT_MAX];
    int t = threadIdx.x;
    for (int i = t; i < NBKT_MAX; i += 1024) h[i] = 0;
    __syncthreads();
    int beg = blockIdx.x * CHUNK;
    int end = min(E, beg + CHUNK);
    for (int j = beg + t; j < end; j += 1024)
        atomicAdd(&h[col[j] >> BKT_BITS], 1);
    __syncthreads();
    for (int i = t; i < nbkt; i += 1024) {
        int c = h[i];
        res[i] = c ? atomicAdd(&cursor[i], c) : 0;  // one reservation atomic per (block,bucket)
    }
    __syncthreads();
    for (int i = t; i < NBKT_MAX; i += 1024) h[i] = 0;  // reuse as local cursor
    __syncthreads();
    for (int j = beg + t; j < end; j += 1024) {
        int c = col[j];
        int b = c >> BKT_BITS;
        int l = atomicAdd(&h[b], 1);
        int pk = (int)(((unsigned)(c & (BKT_SZ - 1)) << 24) | (unsigned)row[j]);  // src < 2^24
        part[res[b] + l] = pk;
    }
}

// ---------------- P4: per-bucket CSR finalize (offs, dis, src), 1024 thr ----------------

__global__ __launch_bounds__(1024) void p4_csr(const int* __restrict__ part,
                                               const int* __restrict__ base,
                                               int* __restrict__ offs, int* __restrict__ srcb,
                                               float* __restrict__ dis, int N, int nbkt) {
    __shared__ int deg[BKT_SZ];
    __shared__ int lofs[BKT_SZ];
    __shared__ int cur[BKT_SZ];
    int b = blockIdx.x, t = threadIdx.x;  // 1024 threads
    int eb = base[b], ee = base[b + 1];
    if (t < BKT_SZ) deg[t] = 0;
    __syncthreads();
    for (int j = eb + t; j < ee; j += 1024)
        atomicAdd(&deg[(unsigned)part[j] >> 24], 1);
    __syncthreads();
    int v = 0;
    if (t < BKT_SZ) { v = deg[t]; lofs[t] = v; }
    __syncthreads();
    for (int off = 1; off < BKT_SZ; off <<= 1) {
        int tmp = (t >= off && t < BKT_SZ) ? lofs[t - off] : 0;
        __syncthreads();
        if (t < BKT_SZ) lofs[t] += tmp;
        __syncthreads();
    }
    if (t < BKT_SZ) {
        int excl = lofs[t] - v;  // exclusive prefix within bucket
        int g = (b << BKT_BITS) + t;
        if (g < N) {
            offs[g] = eb + excl;
            dis[g] = rsqrtf((float)(v + 1));  // +1 self-loop
        }
        deg[t] = excl;  // repurpose: scatter base per local node
        cur[t] = 0;
    }
    if (b == nbkt - 1 && t == 0) offs[N] = ee;  // == E
    __syncthreads();
    for (int j = eb + t; j < ee; j += 1024) {
        int pk = part[j];
        int loc = (unsigned)pk >> 24;
        int l = atomicAdd(&cur[loc], 1);
        srcb[eb + deg[loc] + l] = pk & 0xFFFFFF;  // within-bucket region: L2 write-combined
    }
}

// ---------------- MFMA GEMMs: no LDS, frags direct from global ----------------
// A[m][k]: lane l holds row m=l&15, k=(l>>4)*8+j ; B from WT rows; C/D verified m89/m91.

__global__ __launch_bounds__(256) void mm1_mfma(const float* __restrict__ x,
                                                const _Float16* __restrict__ WT1,
                                                const float* __restrict__ dis,
                                                _Float16* __restrict__ out, int N) {
    int t = threadIdx.x;
    int w = t >> 6, l = t & 63, lr = l & 15, lg = l >> 4;
    int r0 = blockIdx.x * 64 + w * 16;
    if (r0 >= N) return;
    half8 bfrag[4][4];
#pragma unroll
    for (int ct = 0; ct < 4; ++ct)
#pragma unroll
        for (int ks = 0; ks < 4; ++ks)
            bfrag[ct][ks] = *(const half8*)(WT1 + (size_t)(ct * 16 + lr) * IN_F + ks * 32 + lg * 8);
    int ar = min(r0 + lr, N - 1);
    const float* ap = x + (size_t)ar * IN_F + lg * 8;
    f32x4 acc0 = {0.f, 0.f, 0.f, 0.f}, acc1 = acc0, acc2 = acc0, acc3 = acc0;
#pragma unroll
    for (int ks = 0; ks < 4; ++ks) {
        float4 a0 = *(const float4*)(ap + ks * 32);
        float4 a1 = *(const float4*)(ap + ks * 32 + 4);
        half8 a;
        a[0] = (_Float16)a0.x; a[1] = (_Float16)a0.y; a[2] = (_Float16)a0.z; a[3] = (_Float16)a0.w;
        a[4] = (_Float16)a1.x; a[5] = (_Float16)a1.y; a[6] = (_Float16)a1.z; a[7] = (_Float16)a1.w;
        acc0 = __builtin_amdgcn_mfma_f32_16x16x32_f16(a, bfrag[0][ks], acc0, 0, 0, 0);
        acc1 = __builtin_amdgcn_mfma_f32_16x16x32_f16(a, bfrag[1][ks], acc1, 0, 0, 0);
        acc2 = __builtin_amdgcn_mfma_f32_16x16x32_f16(a, bfrag[2][ks], acc2, 0, 0, 0);
        acc3 = __builtin_amdgcn_mfma_f32_16x16x32_f16(a, bfrag[3][ks], acc3, 0, 0, 0);
    }
#pragma unroll
    for (int reg = 0; reg < 4; ++reg) {
        int r = r0 + lg * 4 + reg;
        if (r < N) {
            float d = dis[r];
            _Float16* o = out + (size_t)r * H + lr;
            o[0]  = (_Float16)(d * acc0[reg]);
            o[16] = (_Float16)(d * acc1[reg]);
            o[32] = (_Float16)(d * acc2[reg]);
            o[48] = (_Float16)(d * acc3[reg]);
        }
    }
}

__global__ __launch_bounds__(256) void mm2_mfma(const _Float16* __restrict__ hh,
                                                const float* __restrict__ b1,
                                                const _Float16* __restrict__ WT2,
                                                const float* __restrict__ dis,
                                                _Float16* __restrict__ out, int N) {
    int t = threadIdx.x;
    int w = t >> 6, l = t & 63, lr = l & 15, lg = l >> 4;
    int r0 = blockIdx.x * 64 + w * 16;
    if (r0 >= N) return;
    half8 bfrag[4][2];
#pragma unroll
    for (int ct = 0; ct < 4; ++ct)
#pragma unroll
        for (int ks = 0; ks < 2; ++ks)
            bfrag[ct][ks] = *(const half8*)(WT2 + (size_t)(ct * 16 + lr) * H + ks * 32 + lg * 8);
    float bias0[8], bias1[8];
#pragma unroll
    for (int j = 0; j < 8; ++j) bias0[j] = b1[lg * 8 + j];
#pragma unroll
    for (int j = 0; j < 8; ++j) bias1[j] = b1[32 + lg * 8 + j];
    int ar = min(r0 + lr, N - 1);
    const _Float16* ap = hh + (size_t)ar * H + lg * 8;
    f32x4 acc0 = {0.f, 0.f, 0.f, 0.f}, acc1 = acc0, acc2 = acc0, acc3 = acc0;
#pragma unroll
    for (int ks = 0; ks < 2; ++ks) {
        half8 a = *(const half8*)(ap + ks * 32);
        half8 af;
#pragma unroll
        for (int j = 0; j < 8; ++j) {
            float v = (float)a[j] + (ks ? bias1[j] : bias0[j]);
            af[j] = (_Float16)fmaxf(v, 0.f);
        }
        acc0 = __builtin_amdgcn_mfma_f32_16x16x32_f16(af, bfrag[0][ks], acc0, 0, 0, 0);
        acc1 = __builtin_amdgcn_mfma_f32_16x16x32_f16(af, bfrag[1][ks], acc1, 0, 0, 0);
        acc2 = __builtin_amdgcn_mfma_f32_16x16x32_f16(af, bfrag[2][ks], acc2, 0, 0, 0);
        acc3 = __builtin_amdgcn_mfma_f32_16x16x32_f16(af, bfrag[3][ks], acc3, 0, 0, 0);
    }
#pragma unroll
    for (int reg = 0; reg < 4; ++reg) {
        int r = r0 + lg * 4 + reg;
        if (r < N) {
            float d = dis[r];
            _Float16* o = out + (size_t)r * H + lr;
            o[0]  = (_Float16)(d * acc0[reg]);
            o[16] = (_Float16)(d * acc1[reg]);
            o[32] = (_Float16)(d * acc2[reg]);
            o[48] = (_Float16)(d * acc3[reg]);
        }
    }
}

// out[r,:] = dis[r] * ((hh[r,:] + b) @ W)   W:[64,4]  hh fp16, out f32
__global__ void mm3(const _Float16* __restrict__ hh, const float* __restrict__ b,
                    const float* __restrict__ W, const float* __restrict__ dis,
                    float* __restrict__ out, int N) {
    __shared__ float Wl[H * 4];
    __shared__ float bl[H];
    int t = threadIdx.x;
    if (t < H * 4) Wl[t] = W[t];
    if (t < H) bl[t] = b[t];
    __syncthreads();
    int c = t & 3, rr = t >> 2;
    int r = blockIdx.x * 64 + rr;
    if (r >= N) return;
    const _Float16* h0 = hh + (size_t)r * H;
    float a = 0;
    for (int k = 0; k < H; k += 8) {
        half8 v = *(const half8*)(h0 + k);
#pragma unroll
        for (int j = 0; j < 8; ++j)
            a += ((float)v[j] + bl[k + j]) * Wl[(k + j) * 4 + c];
    }
    out[(size_t)r * 4 + c] = dis[r] * a;
}

// ---------------- aggregation (gather over CSR) — round-9 proven form ----------------

// one wave per node; lane = (slot s = lane>>4, feature-quad f = lane&15 -> 8B).
// Per 32-edge iter: ONE coalesced index load + shfl + 8 gather instrs
// (each gather: 4 rows x 128B = 512B). 32 edges in flight per wave.
__global__ void agg64h(const _Float16* __restrict__ xs, const int* __restrict__ offs,
                       const int* __restrict__ src, const float* __restrict__ dis,
                       _Float16* __restrict__ out, int N) {
    int wid = (blockIdx.x * 256 + threadIdx.x) >> 6;
    int lane = threadIdx.x & 63;
    if (wid >= N) return;
    int s = lane >> 4;   // slot 0..3 (8 edges each per iter)
    int f = lane & 15;   // feature quad: halves [4f, 4f+4)
    int beg = offs[wid], end = offs[wid + 1];
    int deg = end - beg;
    const _Float16* base = xs + (size_t)f * 4;
    float a0 = 0.f, a1 = 0.f, a2 = 0.f, a3 = 0.f;
    int nfull = deg >> 5;
    int j = beg;
    for (int it = 0; it < nfull; ++it, j += 32) {
        int idx = src[j + (lane & 31)];  // one coalesced load: 32 indices
#pragma unroll
        for (int k = 0; k < 8; ++k) {
            int sk = __shfl(idx, s * 8 + k);
            half4 v = *(const half4*)(base + (size_t)sk * 64);
            a0 += (float)v[0]; a1 += (float)v[1]; a2 += (float)v[2]; a3 += (float)v[3];
        }
    }
    for (int jj = j + s; jj < end; jj += 4) {  // tail: slots round-robin
        int sk = src[jj];
        half4 v = *(const half4*)(base + (size_t)sk * 64);
        a0 += (float)v[0]; a1 += (float)v[1]; a2 += (float)v[2]; a3 += (float)v[3];
    }
    // combine the 4 slots
    a0 += __shfl_xor(a0, 16); a0 += __shfl_xor(a0, 32);
    a1 += __shfl_xor(a1, 16); a1 += __shfl_xor(a1, 32);
    a2 += __shfl_xor(a2, 16); a2 += __shfl_xor(a2, 32);
    a3 += __shfl_xor(a3, 16); a3 += __shfl_xor(a3, 32);
    if (s == 0) {
        half4 sv = *(const half4*)(base + (size_t)wid * 64);  // self-loop term
        float d = dis[wid];
        half4 o;
        o[0] = (_Float16)(d * ((float)sv[0] + a0));
        o[1] = (_Float16)(d * ((float)sv[1] + a1));
        o[2] = (_Float16)(d * ((float)sv[2] + a2));
        o[3] = (_Float16)(d * ((float)sv[3] + a3));
        *(half4*)(out + (size_t)wid * 64 + f * 4) = o;
    }
}

// one thread per node, 4 features f32; final output: dis[c]*(inner) + b3
__global__ void agg4(const float* __restrict__ xs, const int* __restrict__ offs,
                     const int* __restrict__ src, const float* __restrict__ dis,
                     const float* __restrict__ b, float* __restrict__ out, int N) {
    int i = blockIdx.x * 256 + threadIdx.x;
    if (i >= N) return;
    float4 v = *(const float4*)(xs + (size_t)i * 4);
    float4 acc = v;  // self-loop term
    int beg = offs[i], end = offs[i + 1];
    int j = beg;
    for (; j + 3 < end; j += 4) {
        int s0 = src[j], s1 = src[j + 1], s2 = src[j + 2], s3 = src[j + 3];
        float4 m0 = *(const float4*)(xs + (size_t)s0 * 4);
        float4 m1 = *(const float4*)(xs + (size_t)s1 * 4);
        float4 m2 = *(const float4*)(xs + (size_t)s2 * 4);
        float4 m3 = *(const float4*)(xs + (size_t)s3 * 4);
        acc.x += m0.x + m1.x + m2.x + m3.x;
        acc.y += m0.y + m1.y + m2.y + m3.y;
        acc.z += m0.z + m1.z + m2.z + m3.z;
        acc.w += m0.w + m1.w + m2.w + m3.w;
    }
    for (; j < end; ++j) {
        float4 m = *(const float4*)(xs + (size_t)src[j] * 4);
        acc.x += m.x; acc.y += m.y; acc.z += m.z; acc.w += m.w;
    }
    float d = dis[i];
    float4 o;
    o.x = b[0] + d * acc.x;
    o.y = b[1] + d * acc.y;
    o.z = b[2] + d * acc.z;
    o.w = b[3] + d * acc.w;
    *(float4*)(out + (size_t)i * 4) = o;
}

// ---------------- host ----------------

extern "C" void kernel_launch(void* const* d_in, const int* in_sizes, int n_in,
                              void* d_out, int out_size, void* d_ws, size_t ws_size,
                              hipStream_t stream) {
    const float* x  = (const float*)d_in[0];
    const int*   ei = (const int*)d_in[1];
    const float* W1 = (const float*)d_in[2];
    const float* b1 = (const float*)d_in[3];
    const float* W2 = (const float*)d_in[4];
    const float* b2 = (const float*)d_in[5];
    const float* W3 = (const float*)d_in[6];
    const float* b3 = (const float*)d_in[7];
    float* out = (float*)d_out;
    (void)n_in; (void)out_size; (void)ws_size;

    const int N = in_sizes[0] / IN_F;
    const int E = in_sizes[1] / 2;
    const int* row = ei;
    const int* col = ei + E;
    const int nbkt = (N + BKT_SZ - 1) >> BKT_BITS;  // 391 for N=100K (<= 512)

    // workspace carve (all 256B-aligned)
    char* w = (char*)d_ws;
    auto carve = [&](size_t bytes) { char* p = w; w += (bytes + 255) & ~(size_t)255; return p; };
    _Float16* bufX  = (_Float16*)carve((size_t)N * H * 2);     // 12.8 MB (mm out / agg in)
    _Float16* bufY  = (_Float16*)carve((size_t)N * H * 2);     // 12.8 MB (agg out / mm in)
    _Float16* WT1   = (_Float16*)carve((size_t)IN_F * H * 2);
    _Float16* WT2   = (_Float16*)carve((size_t)H * H * 2);
    float*  bufC   = (float*)carve((size_t)N * 4 * 4);         // 1.6 MB
    float*  dis    = (float*)carve((size_t)N * 4);
    int*    offs   = (int*)carve((size_t)(N + 1) * 4);
    int*    srcb   = (int*)carve((size_t)E * 4);               // 12.8 MB
    int*    part   = (int*)carve((size_t)E * 4);               // 12.8 MB (packed loc|src)
    int*    bktCnt = (int*)carve((size_t)NBKT_MAX * 4);
    int*    bktBas = (int*)carve((size_t)(NBKT_MAX + 1) * 4);
    int*    bktCur = (int*)carve((size_t)NBKT_MAX * 4);

    (void)hipMemsetAsync(bktCnt, 0, (size_t)nbkt * 4, stream);

    int gE = (E + CHUNK - 1) / CHUNK;  // 391
    int gN = (N + 255) / 256;
    int gMM = (N + 63) / 64;           // 1563
    int gAG = (N + 3) / 4;
    int gPrep = (IN_F * H + H * H + 1023) / 1024;  // 12

    // p1: histogram blocks [0,gE) + weight-prep blocks [gE, gE+gPrep)
    p1_bucket_count<<<gE + gPrep, 1024, 0, stream>>>(col, bktCnt, E, nbkt, gE,
                                                     W1, W2, WT1, WT2);
    p2_bucket_scan<<<1, NBKT_MAX, 0, stream>>>(bktCnt, bktBas, bktCur, nbkt);
    p3_partition<<<gE, 1024, 0, stream>>>(row, col, bktCur, part, E, nbkt);
    p4_csr<<<nbkt, 1024, 0, stream>>>(part, bktBas, offs, srcb, dis, N, nbkt);

    // layer 1: bufX = fp16(dis .* (x@W1)) ; agg -> bufY fp16
    mm1_mfma<<<gMM, 256, 0, stream>>>(x, WT1, dis, bufX, N);
    agg64h<<<gAG, 256, 0, stream>>>(bufX, offs, srcb, dis, bufY, N);
    // layer 2: bufX = fp16(dis .* (relu(bufY+b1)@W2)) ; agg -> bufY fp16
    mm2_mfma<<<gMM, 256, 0, stream>>>(bufY, b1, WT2, dis, bufX, N);
    agg64h<<<gAG, 256, 0, stream>>>(bufX, offs, srcb, dis, bufY, N);
    // layer 3: bufC = dis .* ((bufY+b2)@W3) ; agg (+b3) -> out
    mm3<<<gMM, 256, 0, stream>>>(bufY, b2, W3, dis, bufC, N);
    agg4<<<gN, 256, 0, stream>>>(bufC, offs, srcb, dis, b3, out, N);
}

// Round 14
// 287.436 us; speedup vs baseline: 10.6115x; 1.0136x over previous
//
#include <hip/hip_runtime.h>

#define IN_F 128
#define H 64

#define BKT_BITS 8
#define BKT_SZ 256          // nodes per bucket
#define NBKT_MAX 512        // supports N <= 131072
#define CHUNK 8192          // edges per block in P1/P3

using half8 = __attribute__((ext_vector_type(8))) _Float16;
using half4 = __attribute__((ext_vector_type(4))) _Float16;
using f32x4 = __attribute__((ext_vector_type(4))) float;

// ---------------- P1: per-bucket edge counts (LDS histogram) + fused weight prep ------

__global__ __launch_bounds__(1024) void p1_bucket_count(const int* __restrict__ col,
                                                        int* __restrict__ bucketCnt,
                                                        int E, int nbkt, int gE,
                                                        const float* __restrict__ W1,
                                                        const float* __restrict__ W2,
                                                        _Float16* __restrict__ WT1,
                                                        _Float16* __restrict__ WT2) {
    int t = threadIdx.x;
    if (blockIdx.x >= gE) {
        // weight transpose+convert: 12 blocks x 1024 = 12288 = 8192 (W1) + 4096 (W2)
        int i = (blockIdx.x - gE) * 1024 + t;
        if (i < IN_F * H) {
            int k = i >> 6, c = i & 63;
            WT1[c * IN_F + k] = (_Float16)W1[i];
        } else {
            int j = i - IN_F * H;  // < H*H
            int k = j >> 6, c = j & 63;
            WT2[c * H + k] = (_Float16)W2[j];
        }
        return;
    }
    __shared__ int h[NBKT_MAX];
    for (int i = t; i < NBKT_MAX; i += 1024) h[i] = 0;
    __syncthreads();
    int beg = blockIdx.x * CHUNK;
    int end = min(E, beg + CHUNK);
    for (int j = beg + t; j < end; j += 1024)
        atomicAdd(&h[col[j] >> BKT_BITS], 1);
    __syncthreads();
    for (int i = t; i < nbkt; i += 1024)
        if (h[i]) atomicAdd(&bucketCnt[i], h[i]);
}

// ---------------- P2: scan bucket counts -> bases + cursors (1 block) ----------------

__global__ void p2_bucket_scan(const int* __restrict__ bucketCnt, int* __restrict__ base,
                               int* __restrict__ cursor, int nbkt) {
    __shared__ int s[NBKT_MAX];
    int t = threadIdx.x;  // 512 threads
    int v = (t < nbkt) ? bucketCnt[t] : 0;
    s[t] = v;
    __syncthreads();
    for (int off = 1; off < NBKT_MAX; off <<= 1) {
        int tmp = (t >= off) ? s[t - off] : 0;
        __syncthreads();
        s[t] += tmp;
        __syncthreads();
    }
    if (t < nbkt) {
        int b = s[t] - v;  // exclusive
        base[t] = b;
        cursor[t] = b;
    }
    if (t == nbkt - 1) base[nbkt] = s[t];  // == E
}

// ---------------- P3: partition edges via LDS counting sort, coalesced run writes ------

__global__ __launch_bounds__(1024) void p3_partition(const int* __restrict__ row,
                                                     const int* __restrict__ col,
                                                     int* __restrict__ cursor,
                                                     int* __restrict__ part,
                                                     int E, int nbkt) {
    __shared__ int h[NBKT_MAX];        // histogram -> local cursor
    __shared__ int lb[NBKT_MAX + 1];   // local exclusive scan (+ sentinel)
    __shared__ int res[NBKT_MAX];      // global run starts
    __shared__ int stage[CHUNK];       // 32 KB: bucket-major staged pk
    int t = threadIdx.x;
    for (int i = t; i < NBKT_MAX; i += 1024) h[i] = 0;
    __syncthreads();
    int beg = blockIdx.x * CHUNK;
    int end = min(E, beg + CHUNK);
    int cnt = end - beg;
    for (int j = beg + t; j < end; j += 1024)
        atomicAdd(&h[col[j] >> BKT_BITS], 1);
    __syncthreads();
    // local exclusive scan of h -> lb (512 threads, Hillis-Steele)
    if (t < NBKT_MAX) lb[t] = h[t];
    __syncthreads();
    for (int off = 1; off < NBKT_MAX; off <<= 1) {
        int tmp = (t >= off && t < NBKT_MAX) ? lb[t - off] : 0;
        __syncthreads();
        if (t < NBKT_MAX) lb[t] += tmp;
        __syncthreads();
    }
    if (t < NBKT_MAX) {
        int inc = lb[t];
        lb[t] = inc - h[t];             // exclusive
        if (t == NBKT_MAX - 1) lb[NBKT_MAX] = inc;  // sentinel == cnt
    }
    __syncthreads();
    // global run reservation (one atomic per (block,bucket)); reset h as local cursor
    for (int i = t; i < nbkt; i += 1024) {
        int c = h[i];
        res[i] = c ? atomicAdd(&cursor[i], c) : 0;
    }
    __syncthreads();
    for (int i = t; i < NBKT_MAX; i += 1024) h[i] = 0;
    __syncthreads();
    // stage pk values bucket-major in LDS
    for (int j = beg + t; j < end; j += 1024) {
        int c = col[j];
        int b = c >> BKT_BITS;
        int l = atomicAdd(&h[b], 1);
        int pk = (int)(((unsigned)(c & (BKT_SZ - 1)) << 24) | (unsigned)row[j]);  // src < 2^24
        stage[lb[b] + l] = pk;
    }
    __syncthreads();
    // coalesced write-out: consecutive staged slots -> consecutive global addresses per run
    for (int i = t; i < cnt; i += 1024) {
        // upper_bound over lb: largest b with lb[b] <= i
        int lo = 0, hi = nbkt;
        while (lo + 1 < hi) {
            int mid = (lo + hi) >> 1;
            if (lb[mid] <= i) lo = mid; else hi = mid;
        }
        part[res[lo] + (i - lb[lo])] = stage[i];
    }
}

// ---------------- P4: per-bucket CSR finalize (offs, dis, src), 1024 thr ----------------

__global__ __launch_bounds__(1024) void p4_csr(const int* __restrict__ part,
                                               const int* __restrict__ base,
                                               int* __restrict__ offs, int* __restrict__ srcb,
                                               float* __restrict__ dis, int N, int nbkt) {
    __shared__ int deg[BKT_SZ];
    __shared__ int lofs[BKT_SZ];
    __shared__ int cur[BKT_SZ];
    int b = blockIdx.x, t = threadIdx.x;  // 1024 threads
    int eb = base[b], ee = base[b + 1];
    if (t < BKT_SZ) deg[t] = 0;
    __syncthreads();
    for (int j = eb + t; j < ee; j += 1024)
        atomicAdd(&deg[(unsigned)part[j] >> 24], 1);
    __syncthreads();
    int v = 0;
    if (t < BKT_SZ) { v = deg[t]; lofs[t] = v; }
    __syncthreads();
    for (int off = 1; off < BKT_SZ; off <<= 1) {
        int tmp = (t >= off && t < BKT_SZ) ? lofs[t - off] : 0;
        __syncthreads();
        if (t < BKT_SZ) lofs[t] += tmp;
        __syncthreads();
    }
    if (t < BKT_SZ) {
        int excl = lofs[t] - v;  // exclusive prefix within bucket
        int g = (b << BKT_BITS) + t;
        if (g < N) {
            offs[g] = eb + excl;
            dis[g] = rsqrtf((float)(v + 1));  // +1 self-loop
        }
        deg[t] = excl;  // repurpose: scatter base per local node
        cur[t] = 0;
    }
    if (b == nbkt - 1 && t == 0) offs[N] = ee;  // == E
    __syncthreads();
    for (int j = eb + t; j < ee; j += 1024) {
        int pk = part[j];
        int loc = (unsigned)pk >> 24;
        int l = atomicAdd(&cur[loc], 1);
        srcb[eb + deg[loc] + l] = pk & 0xFFFFFF;  // within-bucket region: L2 write-combined
    }
}

// ---------------- MFMA GEMMs: no LDS, frags direct from global ----------------
// A[m][k]: lane l holds row m=l&15, k=(l>>4)*8+j ; B from WT rows; C/D verified m89/m91.

__global__ __launch_bounds__(256) void mm1_mfma(const float* __restrict__ x,
                                                const _Float16* __restrict__ WT1,
                                                const float* __restrict__ dis,
                                                _Float16* __restrict__ out, int N) {
    int t = threadIdx.x;
    int w = t >> 6, l = t & 63, lr = l & 15, lg = l >> 4;
    int r0 = blockIdx.x * 64 + w * 16;
    if (r0 >= N) return;
    half8 bfrag[4][4];
#pragma unroll
    for (int ct = 0; ct < 4; ++ct)
#pragma unroll
        for (int ks = 0; ks < 4; ++ks)
            bfrag[ct][ks] = *(const half8*)(WT1 + (size_t)(ct * 16 + lr) * IN_F + ks * 32 + lg * 8);
    int ar = min(r0 + lr, N - 1);
    const float* ap = x + (size_t)ar * IN_F + lg * 8;
    f32x4 acc0 = {0.f, 0.f, 0.f, 0.f}, acc1 = acc0, acc2 = acc0, acc3 = acc0;
#pragma unroll
    for (int ks = 0; ks < 4; ++ks) {
        float4 a0 = *(const float4*)(ap + ks * 32);
        float4 a1 = *(const float4*)(ap + ks * 32 + 4);
        half8 a;
        a[0] = (_Float16)a0.x; a[1] = (_Float16)a0.y; a[2] = (_Float16)a0.z; a[3] = (_Float16)a0.w;
        a[4] = (_Float16)a1.x; a[5] = (_Float16)a1.y; a[6] = (_Float16)a1.z; a[7] = (_Float16)a1.w;
        acc0 = __builtin_amdgcn_mfma_f32_16x16x32_f16(a, bfrag[0][ks], acc0, 0, 0, 0);
        acc1 = __builtin_amdgcn_mfma_f32_16x16x32_f16(a, bfrag[1][ks], acc1, 0, 0, 0);
        acc2 = __builtin_amdgcn_mfma_f32_16x16x32_f16(a, bfrag[2][ks], acc2, 0, 0, 0);
        acc3 = __builtin_amdgcn_mfma_f32_16x16x32_f16(a, bfrag[3][ks], acc3, 0, 0, 0);
    }
#pragma unroll
    for (int reg = 0; reg < 4; ++reg) {
        int r = r0 + lg * 4 + reg;
        if (r < N) {
            float d = dis[r];
            _Float16* o = out + (size_t)r * H + lr;
            o[0]  = (_Float16)(d * acc0[reg]);
            o[16] = (_Float16)(d * acc1[reg]);
            o[32] = (_Float16)(d * acc2[reg]);
            o[48] = (_Float16)(d * acc3[reg]);
        }
    }
}

__global__ __launch_bounds__(256) void mm2_mfma(const _Float16* __restrict__ hh,
                                                const float* __restrict__ b1,
                                                const _Float16* __restrict__ WT2,
                                                const float* __restrict__ dis,
                                                _Float16* __restrict__ out, int N) {
    int t = threadIdx.x;
    int w = t >> 6, l = t & 63, lr = l & 15, lg = l >> 4;
    int r0 = blockIdx.x * 64 + w * 16;
    if (r0 >= N) return;
    half8 bfrag[4][2];
#pragma unroll
    for (int ct = 0; ct < 4; ++ct)
#pragma unroll
        for (int ks = 0; ks < 2; ++ks)
            bfrag[ct][ks] = *(const half8*)(WT2 + (size_t)(ct * 16 + lr) * H + ks * 32 + lg * 8);
    float bias0[8], bias1[8];
#pragma unroll
    for (int j = 0; j < 8; ++j) bias0[j] = b1[lg * 8 + j];
#pragma unroll
    for (int j = 0; j < 8; ++j) bias1[j] = b1[32 + lg * 8 + j];
    int ar = min(r0 + lr, N - 1);
    const _Float16* ap = hh + (size_t)ar * H + lg * 8;
    f32x4 acc0 = {0.f, 0.f, 0.f, 0.f}, acc1 = acc0, acc2 = acc0, acc3 = acc0;
#pragma unroll
    for (int ks = 0; ks < 2; ++ks) {
        half8 a = *(const half8*)(ap + ks * 32);
        half8 af;
#pragma unroll
        for (int j = 0; j < 8; ++j) {
            float v = (float)a[j] + (ks ? bias1[j] : bias0[j]);
            af[j] = (_Float16)fmaxf(v, 0.f);
        }
        acc0 = __builtin_amdgcn_mfma_f32_16x16x32_f16(af, bfrag[0][ks], acc0, 0, 0, 0);
        acc1 = __builtin_amdgcn_mfma_f32_16x16x32_f16(af, bfrag[1][ks], acc1, 0, 0, 0);
        acc2 = __builtin_amdgcn_mfma_f32_16x16x32_f16(af, bfrag[2][ks], acc2, 0, 0, 0);
        acc3 = __builtin_amdgcn_mfma_f32_16x16x32_f16(af, bfrag[3][ks], acc3, 0, 0, 0);
    }
#pragma unroll
    for (int reg = 0; reg < 4; ++reg) {
        int r = r0 + lg * 4 + reg;
        if (r < N) {
            float d = dis[r];
            _Float16* o = out + (size_t)r * H + lr;
            o[0]  = (_Float16)(d * acc0[reg]);
            o[16] = (_Float16)(d * acc1[reg]);
            o[32] = (_Float16)(d * acc2[reg]);
            o[48] = (_Float16)(d * acc3[reg]);
        }
    }
}

// out[r,:] = dis[r] * ((hh[r,:] + b) @ W)   W:[64,4]  hh fp16, out f32
__global__ void mm3(const _Float16* __restrict__ hh, const float* __restrict__ b,
                    const float* __restrict__ W, const float* __restrict__ dis,
                    float* __restrict__ out, int N) {
    __shared__ float Wl[H * 4];
    __shared__ float bl[H];
    int t = threadIdx.x;
    if (t < H * 4) Wl[t] = W[t];
    if (t < H) bl[t] = b[t];
    __syncthreads();
    int c = t & 3, rr = t >> 2;
    int r = blockIdx.x * 64 + rr;
    if (r >= N) return;
    const _Float16* h0 = hh + (size_t)r * H;
    float a = 0;
    for (int k = 0; k < H; k += 8) {
        half8 v = *(const half8*)(h0 + k);
#pragma unroll
        for (int j = 0; j < 8; ++j)
            a += ((float)v[j] + bl[k + j]) * Wl[(k + j) * 4 + c];
    }
    out[(size_t)r * 4 + c] = dis[r] * a;
}

// ---------------- aggregation (gather over CSR) — proven form ----------------

// one wave per node; lane = (slot s = lane>>4, feature-quad f = lane&15 -> 8B).
// Per 32-edge iter: ONE coalesced index load + shfl + 8 gather instrs
// (each gather: 4 rows x 128B = 512B). 32 edges in flight per wave.
__global__ void agg64h(const _Float16* __restrict__ xs, const int* __restrict__ offs,
                       const int* __restrict__ src, const float* __restrict__ dis,
                       _Float16* __restrict__ out, int N) {
    int wid = (blockIdx.x * 256 + threadIdx.x) >> 6;
    int lane = threadIdx.x & 63;
    if (wid >= N) return;
    int s = lane >> 4;   // slot 0..3 (8 edges each per iter)
    int f = lane & 15;   // feature quad: halves [4f, 4f+4)
    int beg = offs[wid], end = offs[wid + 1];
    int deg = end - beg;
    const _Float16* base = xs + (size_t)f * 4;
    float a0 = 0.f, a1 = 0.f, a2 = 0.f, a3 = 0.f;
    int nfull = deg >> 5;
    int j = beg;
    for (int it = 0; it < nfull; ++it, j += 32) {
        int idx = src[j + (lane & 31)];  // one coalesced load: 32 indices
#pragma unroll
        for (int k = 0; k < 8; ++k) {
            int sk = __shfl(idx, s * 8 + k);
            half4 v = *(const half4*)(base + (size_t)sk * 64);
            a0 += (float)v[0]; a1 += (float)v[1]; a2 += (float)v[2]; a3 += (float)v[3];
        }
    }
    for (int jj = j + s; jj < end; jj += 4) {  // tail: slots round-robin
        int sk = src[jj];
        half4 v = *(const half4*)(base + (size_t)sk * 64);
        a0 += (float)v[0]; a1 += (float)v[1]; a2 += (float)v[2]; a3 += (float)v[3];
    }
    // combine the 4 slots
    a0 += __shfl_xor(a0, 16); a0 += __shfl_xor(a0, 32);
    a1 += __shfl_xor(a1, 16); a1 += __shfl_xor(a1, 32);
    a2 += __shfl_xor(a2, 16); a2 += __shfl_xor(a2, 32);
    a3 += __shfl_xor(a3, 16); a3 += __shfl_xor(a3, 32);
    if (s == 0) {
        half4 sv = *(const half4*)(base + (size_t)wid * 64);  // self-loop term
        float d = dis[wid];
        half4 o;
        o[0] = (_Float16)(d * ((float)sv[0] + a0));
        o[1] = (_Float16)(d * ((float)sv[1] + a1));
        o[2] = (_Float16)(d * ((float)sv[2] + a2));
        o[3] = (_Float16)(d * ((float)sv[3] + a3));
        *(half4*)(out + (size_t)wid * 64 + f * 4) = o;
    }
}

// one thread per node, 4 features f32; final output: dis[c]*(inner) + b3
__global__ void agg4(const float* __restrict__ xs, const int* __restrict__ offs,
                     const int* __restrict__ src, const float* __restrict__ dis,
                     const float* __restrict__ b, float* __restrict__ out, int N) {
    int i = blockIdx.x * 256 + threadIdx.x;
    if (i >= N) return;
    float4 v = *(const float4*)(xs + (size_t)i * 4);
    float4 acc = v;  // self-loop term
    int beg = offs[i], end = offs[i + 1];
    int j = beg;
    for (; j + 3 < end; j += 4) {
        int s0 = src[j], s1 = src[j + 1], s2 = src[j + 2], s3 = src[j + 3];
        float4 m0 = *(const float4*)(xs + (size_t)s0 * 4);
        float4 m1 = *(const float4*)(xs + (size_t)s1 * 4);
        float4 m2 = *(const float4*)(xs + (size_t)s2 * 4);
        float4 m3 = *(const float4*)(xs + (size_t)s3 * 4);
        acc.x += m0.x + m1.x + m2.x + m3.x;
        acc.y += m0.y + m1.y + m2.y + m3.y;
        acc.z += m0.z + m1.z + m2.z + m3.z;
        acc.w += m0.w + m1.w + m2.w + m3.w;
    }
    for (; j < end; ++j) {
        float4 m = *(const float4*)(xs + (size_t)src[j] * 4);
        acc.x += m.x; acc.y += m.y; acc.z += m.z; acc.w += m.w;
    }
    float d = dis[i];
    float4 o;
    o.x = b[0] + d * acc.x;
    o.y = b[1] + d * acc.y;
    o.z = b[2] + d * acc.z;
    o.w = b[3] + d * acc.w;
    *(float4*)(out + (size_t)i * 4) = o;
}

// ---------------- host ----------------

extern "C" void kernel_launch(void* const* d_in, const int* in_sizes, int n_in,
                              void* d_out, int out_size, void* d_ws, size_t ws_size,
                              hipStream_t stream) {
    const float* x  = (const float*)d_in[0];
    const int*   ei = (const int*)d_in[1];
    const float* W1 = (const float*)d_in[2];
    const float* b1 = (const float*)d_in[3];
    const float* W2 = (const float*)d_in[4];
    const float* b2 = (const float*)d_in[5];
    const float* W3 = (const float*)d_in[6];
    const float* b3 = (const float*)d_in[7];
    float* out = (float*)d_out;
    (void)n_in; (void)out_size; (void)ws_size;

    const int N = in_sizes[0] / IN_F;
    const int E = in_sizes[1] / 2;
    const int* row = ei;
    const int* col = ei + E;
    const int nbkt = (N + BKT_SZ - 1) >> BKT_BITS;  // 391 for N=100K (<= 512)

    // workspace carve (all 256B-aligned)
    char* w = (char*)d_ws;
    auto carve = [&](size_t bytes) { char* p = w; w += (bytes + 255) & ~(size_t)255; return p; };
    _Float16* bufX  = (_Float16*)carve((size_t)N * H * 2);     // 12.8 MB (mm out / agg in)
    _Float16* bufY  = (_Float16*)carve((size_t)N * H * 2);     // 12.8 MB (agg out / mm in)
    _Float16* WT1   = (_Float16*)carve((size_t)IN_F * H * 2);
    _Float16* WT2   = (_Float16*)carve((size_t)H * H * 2);
    float*  bufC   = (float*)carve((size_t)N * 4 * 4);         // 1.6 MB
    float*  dis    = (float*)carve((size_t)N * 4);
    int*    offs   = (int*)carve((size_t)(N + 1) * 4);
    int*    srcb   = (int*)carve((size_t)E * 4);               // 12.8 MB
    int*    part   = (int*)carve((size_t)E * 4);               // 12.8 MB (packed loc|src)
    int*    bktCnt = (int*)carve((size_t)NBKT_MAX * 4);
    int*    bktBas = (int*)carve((size_t)(NBKT_MAX + 1) * 4);
    int*    bktCur = (int*)carve((size_t)NBKT_MAX * 4);

    (void)hipMemsetAsync(bktCnt, 0, (size_t)nbkt * 4, stream);

    int gE = (E + CHUNK - 1) / CHUNK;  // 391
    int gN = (N + 255) / 256;
    int gMM = (N + 63) / 64;           // 1563
    int gAG = (N + 3) / 4;
    int gPrep = (IN_F * H + H * H + 1023) / 1024;  // 12

    // p1: histogram blocks [0,gE) + weight-prep blocks [gE, gE+gPrep)
    p1_bucket_count<<<gE + gPrep, 1024, 0, stream>>>(col, bktCnt, E, nbkt, gE,
                                                     W1, W2, WT1, WT2);
    p2_bucket_scan<<<1, NBKT_MAX, 0, stream>>>(bktCnt, bktBas, bktCur, nbkt);
    p3_partition<<<gE, 1024, 0, stream>>>(row, col, bktCur, part, E, nbkt);
    p4_csr<<<nbkt, 1024, 0, stream>>>(part, bktBas, offs, srcb, dis, N, nbkt);

    // layer 1: bufX = fp16(dis .* (x@W1)) ; agg -> bufY fp16
    mm1_mfma<<<gMM, 256, 0, stream>>>(x, WT1, dis, bufX, N);
    agg64h<<<gAG, 256, 0, stream>>>(bufX, offs, srcb, dis, bufY, N);
    // layer 2: bufX = fp16(dis .* (relu(bufY+b1)@W2)) ; agg -> bufY fp16
    mm2_mfma<<<gMM, 256, 0, stream>>>(bufY, b1, WT2, dis, bufX, N);
    agg64h<<<gAG, 256, 0, stream>>>(bufX, offs, srcb, dis, bufY, N);
    // layer 3: bufC = dis .* ((bufY+b2)@W3) ; agg (+b3) -> out
    mm3<<<gMM, 256, 0, stream>>>(bufY, b2, W3, dis, bufC, N);
    agg4<<<gN, 256, 0, stream>>>(bufC, offs, srcb, dis, b3, out, N);
}